// Round 1
// baseline (2510.413 us; speedup 1.0000x reference)
//
#include <hip/hip_runtime.h>
#include <hip/hip_bf16.h>
#include <math.h>

#define N_NODES 4096
#define IN_DIM  768
#define HID     256
#define HEADS   4
#define OUT_DIM 32
#define ALPHA   0.2f
#define GCOLS   (HEADS*HID)   // 1024

__device__ __forceinline__ float lrelu(float x){ return x > 0.f ? x : ALPHA*x; }
__device__ __forceinline__ float elu_f(float x){ return x > 0.f ? x : expm1f(x); }

// ---------------- GEMM: C[M,Nc] = A[M,K] @ B[Nc,K]^T (+bias) -----------------
// 128x128 tile, BK=16, 256 threads, 8x8 microtile. M % 128 == 0, K % 16 == 0.
// Nc may be < 128 (guarded); Nc % 8 == 0 assumed for float4 stores.
__global__ __launch_bounds__(256)
void gemm_abT(const float* __restrict__ A, const float* __restrict__ B,
              const float* __restrict__ bias, float* __restrict__ C,
              int M, int Nc, int K)
{
    const int BM = 128, BN = 128, BK = 16;
    __shared__ float As[BK][BM];
    __shared__ float Bs[BK][BN];
    const int tid  = threadIdx.x;
    const int bm   = blockIdx.y * BM;
    const int bn   = blockIdx.x * BN;
    const int trow = tid / 16;       // 0..15
    const int tcol = tid % 16;       // 0..15
    const int ar   = tid >> 1;       // 0..127
    const int ak   = (tid & 1) * 8;  // 0 or 8

    float acc[8][8];
#pragma unroll
    for (int i = 0; i < 8; ++i)
#pragma unroll
        for (int j = 0; j < 8; ++j) acc[i][j] = 0.f;

    for (int k0 = 0; k0 < K; k0 += BK) {
        const float* Ap = A + (size_t)(bm + ar) * K + k0 + ak;
        float4 a0 = *(const float4*)Ap;
        float4 a1 = *(const float4*)(Ap + 4);
        float4 b0 = make_float4(0.f,0.f,0.f,0.f), b1 = b0;
        if (bn + ar < Nc) {
            const float* Bp = B + (size_t)(bn + ar) * K + k0 + ak;
            b0 = *(const float4*)Bp;
            b1 = *(const float4*)(Bp + 4);
        }
        __syncthreads();
        As[ak+0][ar]=a0.x; As[ak+1][ar]=a0.y; As[ak+2][ar]=a0.z; As[ak+3][ar]=a0.w;
        As[ak+4][ar]=a1.x; As[ak+5][ar]=a1.y; As[ak+6][ar]=a1.z; As[ak+7][ar]=a1.w;
        Bs[ak+0][ar]=b0.x; Bs[ak+1][ar]=b0.y; Bs[ak+2][ar]=b0.z; Bs[ak+3][ar]=b0.w;
        Bs[ak+4][ar]=b1.x; Bs[ak+5][ar]=b1.y; Bs[ak+6][ar]=b1.z; Bs[ak+7][ar]=b1.w;
        __syncthreads();
#pragma unroll
        for (int kk = 0; kk < BK; ++kk) {
            float4 ra0 = *(const float4*)&As[kk][trow*8];
            float4 ra1 = *(const float4*)&As[kk][trow*8+4];
            float4 rb0 = *(const float4*)&Bs[kk][tcol*8];
            float4 rb1 = *(const float4*)&Bs[kk][tcol*8+4];
            float ra[8] = {ra0.x,ra0.y,ra0.z,ra0.w,ra1.x,ra1.y,ra1.z,ra1.w};
            float rb[8] = {rb0.x,rb0.y,rb0.z,rb0.w,rb1.x,rb1.y,rb1.z,rb1.w};
#pragma unroll
            for (int i = 0; i < 8; ++i)
#pragma unroll
                for (int j = 0; j < 8; ++j)
                    acc[i][j] += ra[i] * rb[j];
        }
    }

    const int col0 = bn + tcol * 8;
    if (col0 < Nc) {
        float bv[8];
#pragma unroll
        for (int j = 0; j < 8; ++j) bv[j] = bias ? bias[col0 + j] : 0.f;
#pragma unroll
        for (int i = 0; i < 8; ++i) {
            const int row = bm + trow*8 + i;
            float4 o0, o1;
            o0.x = acc[i][0]+bv[0]; o0.y = acc[i][1]+bv[1];
            o0.z = acc[i][2]+bv[2]; o0.w = acc[i][3]+bv[3];
            o1.x = acc[i][4]+bv[4]; o1.y = acc[i][5]+bv[5];
            o1.z = acc[i][6]+bv[6]; o1.w = acc[i][7]+bv[7];
            float* Cp = C + (size_t)row * Nc + col0;
            *(float4*)Cp       = o0;
            *(float4*)(Cp + 4) = o1;
        }
    }
}

// ---- s_src[h][n] = g[n][h]·a[h][:HID],  s_dst[h][n] = g[n][h]·a[h][HID:] ----
__global__ __launch_bounds__(256)
void ssd_kernel(const float* __restrict__ g, const float* __restrict__ a,
                float* __restrict__ s_src, float* __restrict__ s_dst)
{
    const int n = blockIdx.x;
    const int h = threadIdx.x >> 6;
    const int l = threadIdx.x & 63;
    const float* grow = g + (size_t)n * GCOLS + h * HID;
    float4 gv = *(const float4*)(grow + l*4);
    float4 as = *(const float4*)(a + h*2*HID + l*4);
    float4 ad = *(const float4*)(a + h*2*HID + HID + l*4);
    float ps = gv.x*as.x + gv.y*as.y + gv.z*as.z + gv.w*as.w;
    float pd = gv.x*ad.x + gv.y*ad.y + gv.z*ad.z + gv.w*ad.w;
#pragma unroll
    for (int off = 32; off; off >>= 1) {
        ps += __shfl_down(ps, off);
        pd += __shfl_down(pd, off);
    }
    if (l == 0) {
        s_src[h*N_NODES + n] = ps;
        s_dst[h*N_NODES + n] = pd;
    }
}

// ---------- per-row online softmax stats: rowM (max), rowZinv (1/sum) -------
__device__ __forceinline__ void mz_merge(float& m, float& z, float om, float oz)
{
    float nm = fmaxf(m, om);
    if (nm == -INFINITY) { m = nm; z = 0.f; return; }
    z = z * __expf(m - nm) + oz * __expf(om - nm);
    m = nm;
}

__global__ __launch_bounds__(256)
void rowmz_kernel(const int* __restrict__ adj, const float* __restrict__ s_src,
                  const float* __restrict__ s_dst, float* __restrict__ rowM,
                  float* __restrict__ rowZinv)
{
    const int i = blockIdx.x;
    const int tid = threadIdx.x;
    float ss[HEADS], m[HEADS], z[HEADS];
#pragma unroll
    for (int h = 0; h < HEADS; ++h) {
        ss[h] = s_src[h*N_NODES + i];
        m[h] = -INFINITY; z[h] = 0.f;
    }
    const int* arow = adj + (size_t)i * N_NODES;
    for (int j = tid; j < N_NODES; j += 256) {
        if (arow[j]) {
#pragma unroll
            for (int h = 0; h < HEADS; ++h) {
                float e = lrelu(ss[h] + s_dst[h*N_NODES + j]);
                if (e > m[h]) { z[h] = z[h] * __expf(m[h] - e) + 1.f; m[h] = e; }
                else          { z[h] += __expf(e - m[h]); }
            }
        }
    }
#pragma unroll
    for (int off = 32; off; off >>= 1) {
#pragma unroll
        for (int h = 0; h < HEADS; ++h) {
            float om = __shfl_down(m[h], off);
            float oz = __shfl_down(z[h], off);
            mz_merge(m[h], z[h], om, oz);
        }
    }
    __shared__ float wm[4][HEADS], wz[4][HEADS];
    const int w = tid >> 6, l = tid & 63;
    if (l == 0) {
#pragma unroll
        for (int h = 0; h < HEADS; ++h) { wm[w][h] = m[h]; wz[w][h] = z[h]; }
    }
    __syncthreads();
    if (tid < HEADS) {
        const int h = tid;
        float M = -INFINITY, Z = 0.f;
#pragma unroll
        for (int ww = 0; ww < 4; ++ww) mz_merge(M, Z, wm[ww][h], wz[ww][h]);
        rowM[h*N_NODES + i]   = M;
        rowZinv[h*N_NODES + i] = 1.f / Z;
    }
}

// --------- hcat[i][h*HID+c] = elu( sum_j P(i,j) * g[j][h*HID+c] ) -----------
// P(i,j) = adj ? exp(lrelu(s_src_i + s_dst_j) - m_i) * zinv_i : 0
// Block: 256 thr, tile BI=32 rows x 256 cols, loop j in BJ=32 tiles.
__global__ __launch_bounds__(256)
void attg_kernel(const float* __restrict__ g, const int* __restrict__ adj,
                 const float* __restrict__ s_src, const float* __restrict__ s_dst,
                 const float* __restrict__ rowM, const float* __restrict__ rowZinv,
                 float* __restrict__ hcat)
{
    const int BI = 32, BJ = 32;
    __shared__ float gs[BJ][HID];      // 32 KB
    __shared__ float Ps[BJ][BI + 4];   // stride 36: 16B-aligned rows, mild write conflicts
    const int h   = blockIdx.y;
    const int i0  = blockIdx.x * BI;
    const int tid = threadIdx.x;
    const int tx  = tid & 63;   // col group: cols tx*4 .. tx*4+3
    const int ty  = tid >> 6;   // row group: rows ty*8 .. ty*8+7
    const int ib  = tid >> 5;   // 0..7: P-compute base row

    float sA[4], mA[4], zA[4];
#pragma unroll
    for (int p = 0; p < 4; ++p) {
        const int ii = ib + p*8;
        sA[p] = s_src[h*N_NODES + i0 + ii];
        mA[p] = rowM[h*N_NODES + i0 + ii];
        zA[p] = rowZinv[h*N_NODES + i0 + ii];
    }

    float acc[8][4];
#pragma unroll
    for (int r = 0; r < 8; ++r)
#pragma unroll
        for (int c = 0; c < 4; ++c) acc[r][c] = 0.f;

    for (int j0 = 0; j0 < N_NODES; j0 += BJ) {
        // global loads into regs
        float4 gl[8];
#pragma unroll
        for (int p = 0; p < 8; ++p) {
            const int row = (tid >> 6) + p*4;      // 0..31
            const int col = (tid & 63) * 4;        // 0..252
            gl[p] = *(const float4*)(g + (size_t)(j0 + row) * GCOLS + h*HID + col);
        }
        float pv[4];
        const int jj = tid & 31;
#pragma unroll
        for (int p = 0; p < 4; ++p) {
            const int ii = ib + p*8;
            const int av = adj[(size_t)(i0 + ii) * N_NODES + j0 + jj];
            const float sd = s_dst[h*N_NODES + j0 + jj];
            const float e = lrelu(sA[p] + sd);
            pv[p] = av ? __expf(e - mA[p]) * zA[p] : 0.f;
        }
        __syncthreads();
#pragma unroll
        for (int p = 0; p < 8; ++p) {
            const int row = (tid >> 6) + p*4;
            const int col = (tid & 63) * 4;
            *(float4*)&gs[row][col] = gl[p];
        }
#pragma unroll
        for (int p = 0; p < 4; ++p) Ps[jj][ib + p*8] = pv[p];
        __syncthreads();

#pragma unroll 8
        for (int j = 0; j < BJ; ++j) {
            float4 gv = *(const float4*)&gs[j][tx*4];
            float4 p0 = *(const float4*)&Ps[j][ty*8];
            float4 p1 = *(const float4*)&Ps[j][ty*8 + 4];
            float pr[8] = {p0.x,p0.y,p0.z,p0.w,p1.x,p1.y,p1.z,p1.w};
#pragma unroll
            for (int r = 0; r < 8; ++r) {
                acc[r][0] += pr[r] * gv.x;
                acc[r][1] += pr[r] * gv.y;
                acc[r][2] += pr[r] * gv.z;
                acc[r][3] += pr[r] * gv.w;
            }
        }
    }

#pragma unroll
    for (int r = 0; r < 8; ++r) {
        const int row = i0 + ty*8 + r;
        float4 o;
        o.x = elu_f(acc[r][0]); o.y = elu_f(acc[r][1]);
        o.z = elu_f(acc[r][2]); o.w = elu_f(acc[r][3]);
        *(float4*)(hcat + (size_t)row * GCOLS + h*HID + tx*4) = o;
    }
}

extern "C" void kernel_launch(void* const* d_in, const int* in_sizes, int n_in,
                              void* d_out, int out_size, void* d_ws, size_t ws_size,
                              hipStream_t stream)
{
    const float* label = (const float*)d_in[0];
    const float* W1    = (const float*)d_in[1];
    const float* a1    = (const float*)d_in[2];
    const float* W2    = (const float*)d_in[3];
    const float* a2    = (const float*)d_in[4];
    const float* out_w = (const float*)d_in[5];
    const float* out_b = (const float*)d_in[6];
    const float* out2_w= (const float*)d_in[7];
    const float* out2_b= (const float*)d_in[8];
    const int*   adj   = (const int*)d_in[9];
    float* out = (float*)d_out;

    float* g    = (float*)d_ws;                         // [4096][1024]
    float* hcat = g    + (size_t)N_NODES * GCOLS;       // [4096][1024]
    float* x1   = hcat + (size_t)N_NODES * GCOLS;       // [4096][768]
    float* ssrc = x1   + (size_t)N_NODES * IN_DIM;      // [4][4096]
    float* sdst = ssrc + (size_t)HEADS * N_NODES;
    float* rM   = sdst + (size_t)HEADS * N_NODES;
    float* rZ   = rM   + (size_t)HEADS * N_NODES;

    auto layer = [&](const float* hin, const float* W, const float* a) {
        // g = hin @ Wflat^T  ([4096,768] x [1024,768]^T)
        gemm_abT<<<dim3(GCOLS/128, N_NODES/128), 256, 0, stream>>>(
            hin, W, nullptr, g, N_NODES, GCOLS, IN_DIM);
        ssd_kernel<<<N_NODES, 256, 0, stream>>>(g, a, ssrc, sdst);
        rowmz_kernel<<<N_NODES, 256, 0, stream>>>(adj, ssrc, sdst, rM, rZ);
        attg_kernel<<<dim3(N_NODES/32, HEADS), 256, 0, stream>>>(
            g, adj, ssrc, sdst, rM, rZ, hcat);
    };

    layer(label, W1, a1);
    // x1 = hcat @ out_w^T + out_b   ([4096,1024] x [768,1024]^T)
    gemm_abT<<<dim3(IN_DIM/128, N_NODES/128), 256, 0, stream>>>(
        hcat, out_w, out_b, x1, N_NODES, IN_DIM, GCOLS);
    layer(x1, W2, a2);
    // out = hcat @ out2_w^T + out2_b ([4096,1024] x [32,1024]^T)
    gemm_abT<<<dim3(1, N_NODES/128), 256, 0, stream>>>(
        hcat, out2_w, out2_b, out, N_NODES, OUT_DIM, GCOLS);
}

// Round 2
// 1694.893 us; speedup vs baseline: 1.4812x; 1.4812x over previous
//
#include <hip/hip_runtime.h>
#include <hip/hip_bf16.h>
#include <math.h>

#define N_NODES 4096
#define IN_DIM  768
#define HID     256
#define HEADS   4
#define OUT_DIM 32
#define ALPHA   0.2f
#define GCOLS   (HEADS*HID)   // 1024
#define NWORDS  (N_NODES/32)  // 128 mask words per row

__device__ __forceinline__ float lrelu(float x){ return x > 0.f ? x : ALPHA*x; }
__device__ __forceinline__ float elu_f(float x){ return x > 0.f ? x : expm1f(x); }

// ---------------- pack adj -> bitmask, layout maskT[jword][i] ----------------
__global__ __launch_bounds__(256)
void pack_kernel(const int* __restrict__ adj, unsigned* __restrict__ maskT)
{
    const int w    = threadIdx.x >> 6;   // wave 0..3
    const int lane = threadIdx.x & 63;
    const int i    = blockIdx.x * 4 + w;
    const int* arow = adj + (size_t)i * N_NODES;
    for (int jt = 0; jt < 64; ++jt) {
        int v = arow[jt*64 + lane];
        unsigned long long b = __ballot(v != 0);
        if (lane == 0) {
            maskT[(size_t)(jt*2    )*N_NODES + i] = (unsigned)b;
            maskT[(size_t)(jt*2 + 1)*N_NODES + i] = (unsigned)(b >> 32);
        }
    }
}

// ---------------- GEMM: C[M,Nc] = A[M,K] @ B[Nc,K]^T (+bias) -----------------
// 128x128 tile, BK=16, 256 threads, 8x8 microtile, register prefetch.
__global__ __launch_bounds__(256)
void gemm_abT(const float* __restrict__ A, const float* __restrict__ B,
              const float* __restrict__ bias, float* __restrict__ C,
              int M, int Nc, int K)
{
    const int BM = 128, BN = 128, BK = 16;
    __shared__ float As[BK][BM];
    __shared__ float Bs[BK][BN];
    const int tid  = threadIdx.x;
    const int bm   = blockIdx.y * BM;
    const int bn   = blockIdx.x * BN;
    const int trow = tid >> 4;       // 0..15
    const int tcol = tid & 15;       // 0..15
    const int ar   = tid >> 1;       // 0..127
    const int ak   = (tid & 1) * 8;  // 0 or 8

    float acc[8][8];
#pragma unroll
    for (int i = 0; i < 8; ++i)
#pragma unroll
        for (int j = 0; j < 8; ++j) acc[i][j] = 0.f;

    const float* Ap = A + (size_t)(bm + ar) * K + ak;
    const bool   bok = (bn + ar < Nc);
    const float* Bp = bok ? B + (size_t)(bn + ar) * K + ak : A;

    float4 a0 = *(const float4*)Ap;
    float4 a1 = *(const float4*)(Ap + 4);
    float4 b0 = make_float4(0,0,0,0), b1 = b0;
    if (bok) { b0 = *(const float4*)Bp; b1 = *(const float4*)(Bp + 4); }

    for (int k0 = 0; k0 < K; k0 += BK) {
        __syncthreads();
        As[ak+0][ar]=a0.x; As[ak+1][ar]=a0.y; As[ak+2][ar]=a0.z; As[ak+3][ar]=a0.w;
        As[ak+4][ar]=a1.x; As[ak+5][ar]=a1.y; As[ak+6][ar]=a1.z; As[ak+7][ar]=a1.w;
        Bs[ak+0][ar]=b0.x; Bs[ak+1][ar]=b0.y; Bs[ak+2][ar]=b0.z; Bs[ak+3][ar]=b0.w;
        Bs[ak+4][ar]=b1.x; Bs[ak+5][ar]=b1.y; Bs[ak+6][ar]=b1.z; Bs[ak+7][ar]=b1.w;
        __syncthreads();
        if (k0 + BK < K) {   // prefetch next K-slab; hides under compute below
            a0 = *(const float4*)(Ap + k0 + BK);
            a1 = *(const float4*)(Ap + k0 + BK + 4);
            if (bok) {
                b0 = *(const float4*)(Bp + k0 + BK);
                b1 = *(const float4*)(Bp + k0 + BK + 4);
            }
        }
#pragma unroll
        for (int kk = 0; kk < BK; ++kk) {
            float4 ra0 = *(const float4*)&As[kk][trow*8];
            float4 ra1 = *(const float4*)&As[kk][trow*8+4];
            float4 rb0 = *(const float4*)&Bs[kk][tcol*8];
            float4 rb1 = *(const float4*)&Bs[kk][tcol*8+4];
            float ra[8] = {ra0.x,ra0.y,ra0.z,ra0.w,ra1.x,ra1.y,ra1.z,ra1.w};
            float rb[8] = {rb0.x,rb0.y,rb0.z,rb0.w,rb1.x,rb1.y,rb1.z,rb1.w};
#pragma unroll
            for (int i = 0; i < 8; ++i)
#pragma unroll
                for (int j = 0; j < 8; ++j)
                    acc[i][j] += ra[i] * rb[j];
        }
    }

    const int col0 = bn + tcol * 8;
    if (col0 < Nc) {
        float bv[8];
#pragma unroll
        for (int j = 0; j < 8; ++j) bv[j] = bias ? bias[col0 + j] : 0.f;
#pragma unroll
        for (int i = 0; i < 8; ++i) {
            const int row = bm + trow*8 + i;
            float4 o0, o1;
            o0.x = acc[i][0]+bv[0]; o0.y = acc[i][1]+bv[1];
            o0.z = acc[i][2]+bv[2]; o0.w = acc[i][3]+bv[3];
            o1.x = acc[i][4]+bv[4]; o1.y = acc[i][5]+bv[5];
            o1.z = acc[i][6]+bv[6]; o1.w = acc[i][7]+bv[7];
            float* Cp = C + (size_t)row * Nc + col0;
            *(float4*)Cp       = o0;
            *(float4*)(Cp + 4) = o1;
        }
    }
}

// ---- s_src[h][n] = g[n][h]·a[h][:HID],  s_dst[h][n] = g[n][h]·a[h][HID:] ----
__global__ __launch_bounds__(256)
void ssd_kernel(const float* __restrict__ g, const float* __restrict__ a,
                float* __restrict__ s_src, float* __restrict__ s_dst)
{
    const int n = blockIdx.x;
    const int h = threadIdx.x >> 6;
    const int l = threadIdx.x & 63;
    const float* grow = g + (size_t)n * GCOLS + h * HID;
    float4 gv = *(const float4*)(grow + l*4);
    float4 as = *(const float4*)(a + h*2*HID + l*4);
    float4 ad = *(const float4*)(a + h*2*HID + HID + l*4);
    float ps = gv.x*as.x + gv.y*as.y + gv.z*as.z + gv.w*as.w;
    float pd = gv.x*ad.x + gv.y*ad.y + gv.z*ad.z + gv.w*ad.w;
#pragma unroll
    for (int off = 32; off; off >>= 1) {
        ps += __shfl_down(ps, off);
        pd += __shfl_down(pd, off);
    }
    if (l == 0) {
        s_src[h*N_NODES + n] = ps;
        s_dst[h*N_NODES + n] = pd;
    }
}

// ----- rowC[h][i] = m + log(Z): two-pass, mask-driven, branch-free ----------
// pass1 uses lrelu monotonicity: row max = lrelu(ss + max_{adj} sd).
__global__ __launch_bounds__(256)
void rowmz_kernel(const unsigned* __restrict__ maskT, const float* __restrict__ s_src,
                  const float* __restrict__ s_dst, float* __restrict__ rowC)
{
    const int i   = blockIdx.x;
    const int tid = threadIdx.x;
    const int w   = tid & 127;       // word index
    const int hp  = tid >> 7;        // 0: heads 0,1 ; 1: heads 2,3
    const unsigned bits = maskT[(size_t)w*N_NODES + i];
    const float* sd0 = s_dst + (size_t)(2*hp  )*N_NODES + w*32;
    const float* sd1 = s_dst + (size_t)(2*hp+1)*N_NODES + w*32;

    float md0 = -INFINITY, md1 = -INFINITY;
#pragma unroll
    for (int k = 0; k < 8; ++k) {
        float4 a4 = *(const float4*)(sd0 + k*4);
        float4 b4 = *(const float4*)(sd1 + k*4);
        md0 = fmaxf(md0, ((bits>>(4*k+0))&1) ? a4.x : -INFINITY);
        md0 = fmaxf(md0, ((bits>>(4*k+1))&1) ? a4.y : -INFINITY);
        md0 = fmaxf(md0, ((bits>>(4*k+2))&1) ? a4.z : -INFINITY);
        md0 = fmaxf(md0, ((bits>>(4*k+3))&1) ? a4.w : -INFINITY);
        md1 = fmaxf(md1, ((bits>>(4*k+0))&1) ? b4.x : -INFINITY);
        md1 = fmaxf(md1, ((bits>>(4*k+1))&1) ? b4.y : -INFINITY);
        md1 = fmaxf(md1, ((bits>>(4*k+2))&1) ? b4.z : -INFINITY);
        md1 = fmaxf(md1, ((bits>>(4*k+3))&1) ? b4.w : -INFINITY);
    }
#pragma unroll
    for (int off = 32; off; off >>= 1) {
        md0 = fmaxf(md0, __shfl_down(md0, off));
        md1 = fmaxf(md1, __shfl_down(md1, off));
    }
    __shared__ float Wr[4][2];
    const int wv = tid >> 6;
    if ((tid & 63) == 0) { Wr[wv][0] = md0; Wr[wv][1] = md1; }
    __syncthreads();
    const float ss0 = s_src[(size_t)(2*hp  )*N_NODES + i];
    const float ss1 = s_src[(size_t)(2*hp+1)*N_NODES + i];
    const float M0 = lrelu(ss0 + fmaxf(Wr[hp*2][0], Wr[hp*2+1][0]));
    const float M1 = lrelu(ss1 + fmaxf(Wr[hp*2][1], Wr[hp*2+1][1]));

    float z0 = 0.f, z1 = 0.f;
#pragma unroll
    for (int k = 0; k < 8; ++k) {
        float4 a4 = *(const float4*)(sd0 + k*4);
        float4 b4 = *(const float4*)(sd1 + k*4);
        z0 += ((bits>>(4*k+0))&1) ? __expf(lrelu(ss0+a4.x)-M0) : 0.f;
        z0 += ((bits>>(4*k+1))&1) ? __expf(lrelu(ss0+a4.y)-M0) : 0.f;
        z0 += ((bits>>(4*k+2))&1) ? __expf(lrelu(ss0+a4.z)-M0) : 0.f;
        z0 += ((bits>>(4*k+3))&1) ? __expf(lrelu(ss0+a4.w)-M0) : 0.f;
        z1 += ((bits>>(4*k+0))&1) ? __expf(lrelu(ss1+b4.x)-M1) : 0.f;
        z1 += ((bits>>(4*k+1))&1) ? __expf(lrelu(ss1+b4.y)-M1) : 0.f;
        z1 += ((bits>>(4*k+2))&1) ? __expf(lrelu(ss1+b4.z)-M1) : 0.f;
        z1 += ((bits>>(4*k+3))&1) ? __expf(lrelu(ss1+b4.w)-M1) : 0.f;
    }
#pragma unroll
    for (int off = 32; off; off >>= 1) {
        z0 += __shfl_down(z0, off);
        z1 += __shfl_down(z1, off);
    }
    __syncthreads();
    if ((tid & 63) == 0) { Wr[wv][0] = z0; Wr[wv][1] = z1; }
    __syncthreads();
    if ((tid & 127) == 0) {
        const float Z0 = Wr[hp*2][0] + Wr[hp*2+1][0];
        const float Z1 = Wr[hp*2][1] + Wr[hp*2+1][1];
        rowC[(size_t)(2*hp  )*N_NODES + i] = M0 + __logf(Z0);
        rowC[(size_t)(2*hp+1)*N_NODES + i] = M1 + __logf(Z1);
    }
}

// --------- part[i][h*HID+c] = sum_{j in half} P(i,j) * g[j][h*HID+c] --------
// P(i,j) = bit ? exp(lrelu(s_src_i + s_dst_j) - rowC_i) : 0
// Block: 128 rows x 128 cols, 256 thr, acc[8][8]; j-half per blockIdx.z.
__global__ __launch_bounds__(256)
void attg_kernel(const float* __restrict__ g, const unsigned* __restrict__ maskT,
                 const float* __restrict__ s_src, const float* __restrict__ rowC,
                 const float* __restrict__ s_dst, float* __restrict__ part0,
                 float* __restrict__ part1)
{
    __shared__ float gs[32][128];      // 16 KB
    __shared__ float Ps[32][132];      // 16.9 KB (pad 132 vs write conflicts)
    __shared__ float sS[128], sC[128];

    const int tid  = threadIdx.x;
    const int h    = blockIdx.y >> 1;
    const int c0   = (blockIdx.y & 1) * 128;
    const int i0   = blockIdx.x * 128;
    const int jbase= blockIdx.z * (N_NODES/2);

    const int tx = tid & 15;           // compute: cols tx*8
    const int ty = tid >> 4;           // compute: rows ty*8
    const int lj = tid & 31;           // load/P: col within j-tile
    const int lr = tid >> 5;           // 0..7

    if (tid < 128) {
        sS[tid] = s_src[(size_t)h*N_NODES + i0 + tid];
        sC[tid] = rowC [(size_t)h*N_NODES + i0 + tid];
    }
    __syncthreads();

    float acc[8][8];
#pragma unroll
    for (int r = 0; r < 8; ++r)
#pragma unroll
        for (int c = 0; c < 8; ++c) acc[r][c] = 0.f;

    const float* gsrc = g + (size_t)h*HID + c0 + lj*4;

    float4 g4[4]; uint4 wb[4]; float sd;
    {
        const int j0 = jbase;
#pragma unroll
        for (int p = 0; p < 4; ++p)
            g4[p] = *(const float4*)(gsrc + (size_t)(j0+lr+8*p)*GCOLS);
        const unsigned* mrow = maskT + (size_t)(j0>>5)*N_NODES + i0 + lr*16;
#pragma unroll
        for (int q = 0; q < 4; ++q) wb[q] = *(const uint4*)(mrow + 4*q);
        sd = s_dst[(size_t)h*N_NODES + j0 + lj];
    }

    for (int t = 0; t < 64; ++t) {
        const int j0 = jbase + t*32;
        // P values from current regs + LDS row constants
        float pv[16];
#pragma unroll
        for (int p = 0; p < 16; ++p) {
            const int ii = lr*16 + p;
            const unsigned wrd = ((const unsigned*)&wb[p>>2])[p&3];
            const float e = lrelu(sS[ii] + sd);
            pv[p] = ((wrd >> lj) & 1) ? __expf(e - sC[ii]) : 0.f;
        }
        __syncthreads();   // prev compute's LDS reads done (drains g4 loads too)
#pragma unroll
        for (int p = 0; p < 4; ++p)
            *(float4*)&gs[lr+8*p][lj*4] = g4[p];
#pragma unroll
        for (int q = 0; q < 4; ++q)
            *(float4*)&Ps[lj][lr*16+4*q] =
                make_float4(pv[4*q], pv[4*q+1], pv[4*q+2], pv[4*q+3]);
        __syncthreads();
        if (t + 1 < 64) {  // prefetch issued AFTER barrier -> hides under FMAs
            const int jn = j0 + 32;
#pragma unroll
            for (int p = 0; p < 4; ++p)
                g4[p] = *(const float4*)(gsrc + (size_t)(jn+lr+8*p)*GCOLS);
            const unsigned* mrow = maskT + (size_t)(jn>>5)*N_NODES + i0 + lr*16;
#pragma unroll
            for (int q = 0; q < 4; ++q) wb[q] = *(const uint4*)(mrow + 4*q);
            sd = s_dst[(size_t)h*N_NODES + jn + lj];
        }
#pragma unroll
        for (int j = 0; j < 32; ++j) {
            float4 ga = *(const float4*)&gs[j][tx*8];
            float4 gb = *(const float4*)&gs[j][tx*8+4];
            float4 pa = *(const float4*)&Ps[j][ty*8];
            float4 pb = *(const float4*)&Ps[j][ty*8+4];
            float gr[8] = {ga.x,ga.y,ga.z,ga.w,gb.x,gb.y,gb.z,gb.w};
            float pr[8] = {pa.x,pa.y,pa.z,pa.w,pb.x,pb.y,pb.z,pb.w};
#pragma unroll
            for (int r = 0; r < 8; ++r)
#pragma unroll
                for (int c = 0; c < 8; ++c)
                    acc[r][c] += pr[r] * gr[c];
        }
    }

    float* dst = (blockIdx.z ? part1 : part0);
#pragma unroll
    for (int r = 0; r < 8; ++r) {
        const int row = i0 + ty*8 + r;
        float* Cp = dst + (size_t)row * GCOLS + h*HID + c0 + tx*8;
        *(float4*)Cp     = make_float4(acc[r][0], acc[r][1], acc[r][2], acc[r][3]);
        *(float4*)(Cp+4) = make_float4(acc[r][4], acc[r][5], acc[r][6], acc[r][7]);
    }
}

// ------------------- io = elu(io + p1), elementwise ------------------------
__global__ __launch_bounds__(256)
void reduce_elu(const float* __restrict__ p1, float* __restrict__ io)
{
    const size_t idx = ((size_t)blockIdx.x * 256 + threadIdx.x) * 4;
    float4 a = *(const float4*)(io + idx);
    float4 b = *(const float4*)(p1 + idx);
    a.x = elu_f(a.x + b.x); a.y = elu_f(a.y + b.y);
    a.z = elu_f(a.z + b.z); a.w = elu_f(a.w + b.w);
    *(float4*)(io + idx) = a;
}

extern "C" void kernel_launch(void* const* d_in, const int* in_sizes, int n_in,
                              void* d_out, int out_size, void* d_ws, size_t ws_size,
                              hipStream_t stream)
{
    const float* label = (const float*)d_in[0];
    const float* W1    = (const float*)d_in[1];
    const float* a1    = (const float*)d_in[2];
    const float* W2    = (const float*)d_in[3];
    const float* a2    = (const float*)d_in[4];
    const float* out_w = (const float*)d_in[5];
    const float* out_b = (const float*)d_in[6];
    const float* out2_w= (const float*)d_in[7];
    const float* out2_b= (const float*)d_in[8];
    const int*   adj   = (const int*)d_in[9];
    float* out = (float*)d_out;

    float* g     = (float*)d_ws;                        // 4M floats
    float* hcat  = g    + (size_t)N_NODES * GCOLS;      // 4M floats (part0 + result)
    float* part1 = hcat + (size_t)N_NODES * GCOLS;      // 4M floats (aliases x1)
    float* x1    = part1;                               // [4096][768] alias: safe by order
    float* ssrc  = part1 + (size_t)N_NODES * GCOLS;
    float* sdst  = ssrc + (size_t)HEADS * N_NODES;
    float* rC    = sdst + (size_t)HEADS * N_NODES;
    unsigned* maskT = (unsigned*)(rC + (size_t)HEADS * N_NODES);  // 512K words

    pack_kernel<<<N_NODES/4, 256, 0, stream>>>(adj, maskT);

    auto layer = [&](const float* hin, const float* W, const float* a) {
        gemm_abT<<<dim3(GCOLS/128, N_NODES/128), 256, 0, stream>>>(
            hin, W, nullptr, g, N_NODES, GCOLS, IN_DIM);
        ssd_kernel<<<N_NODES, 256, 0, stream>>>(g, a, ssrc, sdst);
        rowmz_kernel<<<N_NODES, 256, 0, stream>>>(maskT, ssrc, sdst, rC);
        attg_kernel<<<dim3(N_NODES/128, HEADS*2, 2), 256, 0, stream>>>(
            g, maskT, ssrc, rC, sdst, hcat, part1);
        reduce_elu<<<(N_NODES*GCOLS)/1024, 256, 0, stream>>>(part1, hcat);
    };

    layer(label, W1, a1);
    // x1 = hcat @ out_w^T + out_b  (x1 aliases part1: part1 is dead here)
    gemm_abT<<<dim3(IN_DIM/128, N_NODES/128), 256, 0, stream>>>(
        hcat, out_w, out_b, x1, N_NODES, IN_DIM, GCOLS);
    layer(x1, W2, a2);
    gemm_abT<<<dim3(1, N_NODES/128), 256, 0, stream>>>(
        hcat, out2_w, out2_b, out, N_NODES, OUT_DIM, GCOLS);
}

// Round 3
// 882.070 us; speedup vs baseline: 2.8460x; 1.9215x over previous
//
#include <hip/hip_runtime.h>
#include <hip/hip_bf16.h>
#include <math.h>

#define N_NODES 4096
#define IN_DIM  768
#define HID     256
#define HEADS   4
#define OUT_DIM 32
#define ALPHA   0.2f
#define GCOLS   (HEADS*HID)   // 1024
#define NWORDS  (N_NODES/32)  // 128 mask words per row

typedef unsigned short ushort_t;
typedef short bf16x8 __attribute__((ext_vector_type(8)));
typedef float f32x4 __attribute__((ext_vector_type(4)));

__device__ __forceinline__ float lrelu(float x){ return x > 0.f ? x : ALPHA*x; }
__device__ __forceinline__ float elu_f(float x){ return x > 0.f ? x : expm1f(x); }

__device__ __forceinline__ ushort_t f2bf(float x){
    unsigned u = __float_as_uint(x);
    return (ushort_t)((u + 0x7FFFu + ((u >> 16) & 1u)) >> 16);
}
__device__ __forceinline__ float bf2f(ushort_t h){
    return __uint_as_float(((unsigned)h) << 16);
}
__device__ __forceinline__ void gload16(const void* g, void* l){
    __builtin_amdgcn_global_load_lds((const __attribute__((address_space(1))) void*)(g),
                                     (__attribute__((address_space(3))) void*)(l), 16, 0, 0);
}

// ---------------- pack adj -> bitmask maskJ[i][jword] -----------------------
__global__ __launch_bounds__(256)
void pack_kernel(const int* __restrict__ adj, unsigned* __restrict__ maskJ)
{
    const int w    = threadIdx.x >> 6;
    const int lane = threadIdx.x & 63;
    const int i    = blockIdx.x * 4 + w;
    const int* arow = adj + (size_t)i * N_NODES;
    for (int jt = 0; jt < 64; ++jt) {
        unsigned long long b = __ballot(arow[jt*64 + lane] != 0);
        if (lane == 0) {
            maskJ[(size_t)i*NWORDS + jt*2    ] = (unsigned)b;
            maskJ[(size_t)i*NWORDS + jt*2 + 1] = (unsigned)(b >> 32);
        }
    }
}

// ---------------- fp32 -> bf16 hi/lo split ----------------------------------
__global__ __launch_bounds__(256)
void cvt_hilo(const float* __restrict__ x, ushort_t* __restrict__ hi,
              ushort_t* __restrict__ lo, int n)
{
    const int idx = (blockIdx.x*256 + threadIdx.x)*4;
    if (idx >= n) return;
    float4 v = *(const float4*)(x + idx);
    ushort4 h, l;
    h.x = f2bf(v.x); l.x = f2bf(v.x - bf2f(h.x));
    h.y = f2bf(v.y); l.y = f2bf(v.y - bf2f(h.y));
    h.z = f2bf(v.z); l.z = f2bf(v.z - bf2f(h.z));
    h.w = f2bf(v.w); l.w = f2bf(v.w - bf2f(h.w));
    *(ushort4*)(hi + idx) = h;
    *(ushort4*)(lo + idx) = l;
}

__global__ __launch_bounds__(256)
void zero_kernel(float* p, int n){
    int i = blockIdx.x*256 + threadIdx.x;
    if (i < n) p[i] = 0.f;
}

// ------------- hi/lo split-bf16 MFMA GEMM: C[M,N] = A[M,K] @ B[N,K]^T -------
// 3-term (AhBh + AhBl + AlBh), 128x128 tile, BK=32, 256 thr, 64x64 wave tiles.
// Optional: bias add; output fp32 OR split hi/lo bf16; optional attention
// s_src/s_dst atomic reduction (for gT = W @ h^T GEMMs, avec = a[h][2*HID]).
__global__ __launch_bounds__(256)
void gemm_hilo(const ushort_t* __restrict__ Ahi, const ushort_t* __restrict__ Alo,
               const ushort_t* __restrict__ Bhi, const ushort_t* __restrict__ Blo,
               const float* __restrict__ bias, float* __restrict__ outF,
               ushort_t* __restrict__ outHi, ushort_t* __restrict__ outLo,
               const float* __restrict__ avec, float* __restrict__ ssrc,
               float* __restrict__ sdst, int M, int N, int K)
{
    __shared__ ushort_t sA[2][2][128*32];
    __shared__ ushort_t sB[2][2][128*32];
    const int tid  = threadIdx.x;
    const int w    = tid >> 6, lane = tid & 63;
    const int l15  = lane & 15, l4 = lane >> 4;
    const int wr   = w >> 1, wcl = w & 1;
    const int m0   = blockIdx.y * 128, n0 = blockIdx.x * 128;

    f32x4 acc[4][4];
#pragma unroll
    for (int r = 0; r < 4; ++r)
#pragma unroll
        for (int t = 0; t < 4; ++t) acc[r][t] = (f32x4){0.f,0.f,0.f,0.f};

    auto stage = [&](int buf, int k0){
#pragma unroll
        for (int s = 0; s < 2; ++s) {
            const int rr = w*32 + s*16;
            const int gr = rr + (lane >> 2);
            const int gc = k0 + (lane & 3)*8;
            gload16(Ahi + (size_t)(m0+gr)*K + gc, &sA[buf][0][rr*32]);
            gload16(Alo + (size_t)(m0+gr)*K + gc, &sA[buf][1][rr*32]);
            int br = n0 + gr; if (br >= N) br = N-1;
            gload16(Bhi + (size_t)br*K + gc, &sB[buf][0][rr*32]);
            gload16(Blo + (size_t)br*K + gc, &sB[buf][1][rr*32]);
        }
    };

    stage(0, 0);
    int buf = 0;
    for (int k0 = 0; k0 < K; k0 += 32) {
        __syncthreads();               // drains prev stage (vmcnt) + compute
        if (k0 + 32 < K) stage(buf^1, k0 + 32);
        bf16x8 ah[4], al[4], bh[4], bl[4];
#pragma unroll
        for (int r = 0; r < 4; ++r) {
            const int off = (wr*64 + r*16 + l15)*32 + l4*8;
            ah[r] = *(const bf16x8*)&sA[buf][0][off];
            al[r] = *(const bf16x8*)&sA[buf][1][off];
        }
#pragma unroll
        for (int t = 0; t < 4; ++t) {
            const int off = (wcl*64 + t*16 + l15)*32 + l4*8;
            bh[t] = *(const bf16x8*)&sB[buf][0][off];
            bl[t] = *(const bf16x8*)&sB[buf][1][off];
        }
#pragma unroll
        for (int r = 0; r < 4; ++r)
#pragma unroll
            for (int t = 0; t < 4; ++t) {
                acc[r][t] = __builtin_amdgcn_mfma_f32_16x16x32_bf16(ah[r], bh[t], acc[r][t], 0,0,0);
                acc[r][t] = __builtin_amdgcn_mfma_f32_16x16x32_bf16(ah[r], bl[t], acc[r][t], 0,0,0);
                acc[r][t] = __builtin_amdgcn_mfma_f32_16x16x32_bf16(al[r], bh[t], acc[r][t], 0,0,0);
            }
        buf ^= 1;
    }

    const int hdr = m0 >> 8;     // head (gT GEMM: rows are head*HID+c)
    if (avec) {
        float as[4][4], ad[4][4];
#pragma unroll
        for (int r = 0; r < 4; ++r)
#pragma unroll
            for (int g = 0; g < 4; ++g) {
                const int aid = (m0 + wr*64 + r*16 + l4*4 + g) & (HID-1);
                as[r][g] = avec[hdr*2*HID + aid];
                ad[r][g] = avec[hdr*2*HID + HID + aid];
            }
#pragma unroll
        for (int t = 0; t < 4; ++t) {
            float ps = 0.f, pd = 0.f;
#pragma unroll
            for (int r = 0; r < 4; ++r)
#pragma unroll
                for (int g = 0; g < 4; ++g) {
                    ps += acc[r][t][g] * as[r][g];
                    pd += acc[r][t][g] * ad[r][g];
                }
            ps += __shfl_xor(ps, 16); ps += __shfl_xor(ps, 32);
            pd += __shfl_xor(pd, 16); pd += __shfl_xor(pd, 32);
            if (lane < 16) {
                const int n = n0 + wcl*64 + t*16 + lane;
                atomicAdd(&ssrc[(size_t)hdr*N_NODES + n], ps);
                atomicAdd(&sdst[(size_t)hdr*N_NODES + n], pd);
            }
        }
    }

#pragma unroll
    for (int r = 0; r < 4; ++r)
#pragma unroll
        for (int t = 0; t < 4; ++t)
#pragma unroll
            for (int g = 0; g < 4; ++g) {
                const int row = m0 + wr*64 + r*16 + l4*4 + g;
                const int col = n0 + wcl*64 + t*16 + l15;
                if (col < N) {
                    float v = acc[r][t][g] + (bias ? bias[col] : 0.f);
                    if (outF) outF[(size_t)row*N + col] = v;
                    else {
                        ushort_t hv = f2bf(v);
                        outHi[(size_t)row*N + col] = hv;
                        outLo[(size_t)row*N + col] = f2bf(v - bf2f(hv));
                    }
                }
            }
}

// ----- rowC[h][i] = m + log(Z): two-pass, mask-driven, branch-free ----------
__global__ __launch_bounds__(256)
void rowmz_kernel(const unsigned* __restrict__ maskJ, const float* __restrict__ s_src,
                  const float* __restrict__ s_dst, float* __restrict__ rowC)
{
    const int i   = blockIdx.x;
    const int tid = threadIdx.x;
    const int w   = tid & 127;
    const int hp  = tid >> 7;
    const unsigned bits = maskJ[(size_t)i*NWORDS + w];
    const float* sd0 = s_dst + (size_t)(2*hp  )*N_NODES + w*32;
    const float* sd1 = s_dst + (size_t)(2*hp+1)*N_NODES + w*32;

    float md0 = -INFINITY, md1 = -INFINITY;
#pragma unroll
    for (int k = 0; k < 8; ++k) {
        float4 a4 = *(const float4*)(sd0 + k*4);
        float4 b4 = *(const float4*)(sd1 + k*4);
        md0 = fmaxf(md0, ((bits>>(4*k+0))&1) ? a4.x : -INFINITY);
        md0 = fmaxf(md0, ((bits>>(4*k+1))&1) ? a4.y : -INFINITY);
        md0 = fmaxf(md0, ((bits>>(4*k+2))&1) ? a4.z : -INFINITY);
        md0 = fmaxf(md0, ((bits>>(4*k+3))&1) ? a4.w : -INFINITY);
        md1 = fmaxf(md1, ((bits>>(4*k+0))&1) ? b4.x : -INFINITY);
        md1 = fmaxf(md1, ((bits>>(4*k+1))&1) ? b4.y : -INFINITY);
        md1 = fmaxf(md1, ((bits>>(4*k+2))&1) ? b4.z : -INFINITY);
        md1 = fmaxf(md1, ((bits>>(4*k+3))&1) ? b4.w : -INFINITY);
    }
#pragma unroll
    for (int off = 32; off; off >>= 1) {
        md0 = fmaxf(md0, __shfl_down(md0, off));
        md1 = fmaxf(md1, __shfl_down(md1, off));
    }
    __shared__ float Wr[4][2];
    const int wv = tid >> 6;
    if ((tid & 63) == 0) { Wr[wv][0] = md0; Wr[wv][1] = md1; }
    __syncthreads();
    const float ss0 = s_src[(size_t)(2*hp  )*N_NODES + i];
    const float ss1 = s_src[(size_t)(2*hp+1)*N_NODES + i];
    const float M0 = lrelu(ss0 + fmaxf(Wr[hp*2][0], Wr[hp*2+1][0]));
    const float M1 = lrelu(ss1 + fmaxf(Wr[hp*2][1], Wr[hp*2+1][1]));

    float z0 = 0.f, z1 = 0.f;
#pragma unroll
    for (int k = 0; k < 8; ++k) {
        float4 a4 = *(const float4*)(sd0 + k*4);
        float4 b4 = *(const float4*)(sd1 + k*4);
        z0 += ((bits>>(4*k+0))&1) ? __expf(lrelu(ss0+a4.x)-M0) : 0.f;
        z0 += ((bits>>(4*k+1))&1) ? __expf(lrelu(ss0+a4.y)-M0) : 0.f;
        z0 += ((bits>>(4*k+2))&1) ? __expf(lrelu(ss0+a4.z)-M0) : 0.f;
        z0 += ((bits>>(4*k+3))&1) ? __expf(lrelu(ss0+a4.w)-M0) : 0.f;
        z1 += ((bits>>(4*k+0))&1) ? __expf(lrelu(ss1+b4.x)-M1) : 0.f;
        z1 += ((bits>>(4*k+1))&1) ? __expf(lrelu(ss1+b4.y)-M1) : 0.f;
        z1 += ((bits>>(4*k+2))&1) ? __expf(lrelu(ss1+b4.z)-M1) : 0.f;
        z1 += ((bits>>(4*k+3))&1) ? __expf(lrelu(ss1+b4.w)-M1) : 0.f;
    }
#pragma unroll
    for (int off = 32; off; off >>= 1) {
        z0 += __shfl_down(z0, off);
        z1 += __shfl_down(z1, off);
    }
    __syncthreads();
    if ((tid & 63) == 0) { Wr[wv][0] = z0; Wr[wv][1] = z1; }
    __syncthreads();
    if ((tid & 127) == 0) {
        rowC[(size_t)(2*hp  )*N_NODES + i] = M0 + __logf(Wr[hp*2][0] + Wr[hp*2+1][0]);
        rowC[(size_t)(2*hp+1)*N_NODES + i] = M1 + __logf(Wr[hp*2][1] + Wr[hp*2+1][1]);
    }
}

// -------- attg: part[i][h*HID+c] = sum_{j in half} P(i,j) * g[j][c] ---------
// MFMA: A = P (bf16, built in registers), B = gT tile (bf16, LDS staged).
// 512 thr / 8 waves (2 x 4), block tile 128 i x 256 c, BJ=32, j-half = blockIdx.z.
__global__ __launch_bounds__(512)
void attg_kernel(const ushort_t* __restrict__ gThi, const unsigned* __restrict__ maskJ,
                 const float* __restrict__ s_src, const float* __restrict__ rowC,
                 const float* __restrict__ s_dst, float* __restrict__ part0,
                 float* __restrict__ part1)
{
    __shared__ ushort_t gsT[2][256*32];
    const int tid  = threadIdx.x;
    const int w    = tid >> 6, lane = tid & 63;
    const int l15  = lane & 15, l4 = lane >> 4;
    const int wih  = w >> 2, wc = w & 3;
    const int h    = blockIdx.y;
    const int i0   = blockIdx.x * 128;
    const int z    = blockIdx.z;
    const int jbase = z * (N_NODES/2);

    float ssv[4], Cv[4];
#pragma unroll
    for (int r = 0; r < 4; ++r) {
        const int ig = i0 + wih*64 + r*16 + l15;
        ssv[r] = s_src[(size_t)h*N_NODES + ig];
        Cv[r]  = rowC [(size_t)h*N_NODES + ig];
    }

    f32x4 acc[4][4];
#pragma unroll
    for (int r = 0; r < 4; ++r)
#pragma unroll
        for (int t = 0; t < 4; ++t) acc[r][t] = (f32x4){0.f,0.f,0.f,0.f};

    auto stage = [&](int buf, int j0){
#pragma unroll
        for (int s = 0; s < 2; ++s) {
            const int rr = w*32 + s*16;               // c-row chunk 0..255
            const int cr = rr + (lane >> 2);
            gload16(gThi + (size_t)(h*HID + cr)*N_NODES + j0 + (lane & 3)*8,
                    &gsT[buf][rr*32]);
        }
    };

    stage(0, jbase);
    int buf = 0;
    for (int tt = 0; tt < 64; ++tt) {
        const int j0 = jbase + tt*32;
        __syncthreads();
        if (tt + 1 < 64) stage(buf^1, j0 + 32);

        float4 sd0 = *(const float4*)(s_dst + (size_t)h*N_NODES + j0 + l4*8);
        float4 sd1 = *(const float4*)(s_dst + (size_t)h*N_NODES + j0 + l4*8 + 4);
        float sdv[8] = {sd0.x,sd0.y,sd0.z,sd0.w,sd1.x,sd1.y,sd1.z,sd1.w};
        bf16x8 af[4];
#pragma unroll
        for (int r = 0; r < 4; ++r) {
            const unsigned mw = maskJ[(size_t)(i0 + wih*64 + r*16 + l15)*NWORDS + (j0 >> 5)];
#pragma unroll
            for (int q = 0; q < 8; ++q) {
                float e = lrelu(ssv[r] + sdv[q]);
                float pv = ((mw >> (l4*8 + q)) & 1u) ? __expf(e - Cv[r]) : 0.f;
                af[r][q] = (short)f2bf(pv);
            }
        }
#pragma unroll
        for (int t = 0; t < 4; ++t) {
            const bf16x8 bf = *(const bf16x8*)&gsT[buf][(wc*64 + t*16 + l15)*32 + l4*8];
#pragma unroll
            for (int r = 0; r < 4; ++r)
                acc[r][t] = __builtin_amdgcn_mfma_f32_16x16x32_bf16(af[r], bf, acc[r][t], 0,0,0);
        }
        buf ^= 1;
    }

    float* dst = z ? part1 : part0;
#pragma unroll
    for (int r = 0; r < 4; ++r)
#pragma unroll
        for (int t = 0; t < 4; ++t)
#pragma unroll
            for (int g = 0; g < 4; ++g) {
                const int row = i0 + wih*64 + r*16 + l4*4 + g;
                const int col = h*HID + wc*64 + t*16 + l15;
                dst[(size_t)row*GCOLS + col] = acc[r][t][g];
            }
}

// ---------- hcat (hi/lo bf16) = elu(part0 + part1) --------------------------
__global__ __launch_bounds__(256)
void reduce_elu2(const float* __restrict__ p0, const float* __restrict__ p1,
                 ushort_t* __restrict__ hi, ushort_t* __restrict__ lo)
{
    const size_t idx = ((size_t)blockIdx.x*256 + threadIdx.x)*4;
    float4 a = *(const float4*)(p0 + idx);
    float4 b = *(const float4*)(p1 + idx);
    float v0 = elu_f(a.x + b.x), v1 = elu_f(a.y + b.y);
    float v2 = elu_f(a.z + b.z), v3 = elu_f(a.w + b.w);
    ushort4 h, l;
    h.x = f2bf(v0); l.x = f2bf(v0 - bf2f(h.x));
    h.y = f2bf(v1); l.y = f2bf(v1 - bf2f(h.y));
    h.z = f2bf(v2); l.z = f2bf(v2 - bf2f(h.z));
    h.w = f2bf(v3); l.w = f2bf(v3 - bf2f(h.w));
    *(ushort4*)(hi + idx) = h;
    *(ushort4*)(lo + idx) = l;
}

extern "C" void kernel_launch(void* const* d_in, const int* in_sizes, int n_in,
                              void* d_out, int out_size, void* d_ws, size_t ws_size,
                              hipStream_t stream)
{
    const float* label = (const float*)d_in[0];
    const float* W1    = (const float*)d_in[1];
    const float* a1    = (const float*)d_in[2];
    const float* W2    = (const float*)d_in[3];
    const float* a2    = (const float*)d_in[4];
    const float* out_w = (const float*)d_in[5];
    const float* out_b = (const float*)d_in[6];
    const float* out2_w= (const float*)d_in[7];
    const float* out2_b= (const float*)d_in[8];
    const int*   adj   = (const int*)d_in[9];
    float* out = (float*)d_out;

    char* p = (char*)d_ws;
    auto alloc = [&](size_t bytes){ char* r = p; p += (bytes + 255) & ~(size_t)255; return r; };
    float*    part0 = (float*)   alloc((size_t)N_NODES*GCOLS*4);      // 16 MB
    float*    part1 = (float*)   alloc((size_t)N_NODES*GCOLS*4);      // 16 MB
    ushort_t* gThi  = (ushort_t*)alloc((size_t)GCOLS*N_NODES*2);      // 8 MB
    ushort_t* gTlo  = (ushort_t*)alloc((size_t)GCOLS*N_NODES*2);      // 8 MB
    ushort_t* hchi  = (ushort_t*)alloc((size_t)N_NODES*GCOLS*2);      // 8 MB
    ushort_t* hclo  = (ushort_t*)alloc((size_t)N_NODES*GCOLS*2);      // 8 MB
    ushort_t* xlhi  = (ushort_t*)alloc((size_t)N_NODES*IN_DIM*2);     // 6 MB (label, then x1)
    ushort_t* xllo  = (ushort_t*)alloc((size_t)N_NODES*IN_DIM*2);     // 6 MB
    ushort_t* w1hi  = (ushort_t*)alloc((size_t)GCOLS*IN_DIM*2);
    ushort_t* w1lo  = (ushort_t*)alloc((size_t)GCOLS*IN_DIM*2);
    ushort_t* w2hi  = (ushort_t*)alloc((size_t)GCOLS*IN_DIM*2);
    ushort_t* w2lo  = (ushort_t*)alloc((size_t)GCOLS*IN_DIM*2);
    ushort_t* owhi  = (ushort_t*)alloc((size_t)IN_DIM*GCOLS*2);
    ushort_t* owlo  = (ushort_t*)alloc((size_t)IN_DIM*GCOLS*2);
    ushort_t* o2hi  = (ushort_t*)alloc((size_t)OUT_DIM*GCOLS*2);
    ushort_t* o2lo  = (ushort_t*)alloc((size_t)OUT_DIM*GCOLS*2);
    unsigned* maskJ = (unsigned*)alloc((size_t)N_NODES*NWORDS*4);     // 2 MB
    float*    ssrc  = (float*)   alloc((size_t)HEADS*N_NODES*4);
    float*    sdst  = (float*)   alloc((size_t)HEADS*N_NODES*4);
    float*    rC    = (float*)   alloc((size_t)HEADS*N_NODES*4);

    pack_kernel<<<N_NODES/4, 256, 0, stream>>>(adj, maskJ);
    cvt_hilo<<<(N_NODES*IN_DIM)/1024, 256, 0, stream>>>(label, xlhi, xllo, N_NODES*IN_DIM);
    cvt_hilo<<<(GCOLS*IN_DIM)/1024, 256, 0, stream>>>(W1, w1hi, w1lo, GCOLS*IN_DIM);
    cvt_hilo<<<(GCOLS*IN_DIM)/1024, 256, 0, stream>>>(W2, w2hi, w2lo, GCOLS*IN_DIM);
    cvt_hilo<<<(IN_DIM*GCOLS)/1024, 256, 0, stream>>>(out_w, owhi, owlo, IN_DIM*GCOLS);
    cvt_hilo<<<(OUT_DIM*GCOLS)/1024, 256, 0, stream>>>(out2_w, o2hi, o2lo, OUT_DIM*GCOLS);

    auto layer = [&](const ushort_t* Whi, const ushort_t* Wlo, const float* avec,
                     const ushort_t* hhi, const ushort_t* hlo, int K) {
        zero_kernel<<<(2*HEADS*N_NODES)/256, 256, 0, stream>>>(ssrc, 2*HEADS*N_NODES);
        // gT[c][j] (+ s_src/s_dst atomics):  gT = W @ h^T
        gemm_hilo<<<dim3(N_NODES/128, GCOLS/128), 256, 0, stream>>>(
            Whi, Wlo, hhi, hlo, nullptr, nullptr, gThi, gTlo,
            avec, ssrc, sdst, GCOLS, N_NODES, K);
        rowmz_kernel<<<N_NODES, 256, 0, stream>>>(maskJ, ssrc, sdst, rC);
        attg_kernel<<<dim3(N_NODES/128, HEADS, 2), 512, 0, stream>>>(
            gThi, maskJ, ssrc, rC, sdst, part0, part1);
        reduce_elu2<<<(N_NODES*GCOLS)/1024, 256, 0, stream>>>(part0, part1, hchi, hclo);
    };

    layer(w1hi, w1lo, a1, xlhi, xllo, IN_DIM);
    // x1 = hcat @ out_w^T + out_b  -> split bf16 (overwrites label slot)
    gemm_hilo<<<dim3(IN_DIM/128, N_NODES/128), 256, 0, stream>>>(
        hchi, hclo, owhi, owlo, out_b, nullptr, xlhi, xllo,
        nullptr, nullptr, nullptr, N_NODES, IN_DIM, GCOLS);
    layer(w2hi, w2lo, a2, xlhi, xllo, IN_DIM);
    // out = hcat @ out2_w^T + out2_b  (fp32, N=32 guarded)
    gemm_hilo<<<dim3(1, N_NODES/128), 256, 0, stream>>>(
        hchi, hclo, o2hi, o2lo, out2_b, out, nullptr, nullptr,
        nullptr, nullptr, nullptr, N_NODES, OUT_DIM, GCOLS);
}

// Round 4
// 671.610 us; speedup vs baseline: 3.7379x; 1.3134x over previous
//
#include <hip/hip_runtime.h>
#include <hip/hip_bf16.h>
#include <math.h>

#define N_NODES 4096
#define IN_DIM  768
#define HID     256
#define HEADS   4
#define OUT_DIM 32
#define ALPHA   0.2f
#define GCOLS   (HEADS*HID)   // 1024
#define NWORDS  (N_NODES/32)  // 128 mask words per row
#define LOG2E   1.4426950408889634f

typedef unsigned short ushort_t;
typedef short bf16x8 __attribute__((ext_vector_type(8)));
typedef float f32x4 __attribute__((ext_vector_type(4)));

__device__ __forceinline__ float elu_f(float x){ return x > 0.f ? x : expm1f(x); }

__device__ __forceinline__ float fexp2(float x){
#if __has_builtin(__builtin_amdgcn_exp2f)
    return __builtin_amdgcn_exp2f(x);
#else
    return exp2f(x);
#endif
}

__device__ __forceinline__ ushort_t f2bf(float x){
    unsigned u = __float_as_uint(x);
    return (ushort_t)((u + 0x7FFFu + ((u >> 16) & 1u)) >> 16);
}
__device__ __forceinline__ float bf2f(ushort_t h){
    return __uint_as_float(((unsigned)h) << 16);
}
__device__ __forceinline__ void gload16(const void* g, void* l){
    __builtin_amdgcn_global_load_lds((const __attribute__((address_space(1))) void*)(g),
                                     (__attribute__((address_space(3))) void*)(l), 16, 0, 0);
}

// ---------------- pack adj -> bitmask maskJ[i][jword] -----------------------
__global__ __launch_bounds__(256)
void pack_kernel(const int* __restrict__ adj, unsigned* __restrict__ maskJ)
{
    const int w    = threadIdx.x >> 6;
    const int lane = threadIdx.x & 63;
    const int i    = blockIdx.x * 4 + w;
    const int* arow = adj + (size_t)i * N_NODES;
    for (int jt = 0; jt < 64; ++jt) {
        unsigned long long b = __ballot(arow[jt*64 + lane] != 0);
        if (lane == 0) {
            maskJ[(size_t)i*NWORDS + jt*2    ] = (unsigned)b;
            maskJ[(size_t)i*NWORDS + jt*2 + 1] = (unsigned)(b >> 32);
        }
    }
}

// ---------------- fp32 -> bf16 hi/lo split ----------------------------------
__global__ __launch_bounds__(256)
void cvt_hilo(const float* __restrict__ x, ushort_t* __restrict__ hi,
              ushort_t* __restrict__ lo, int n)
{
    const int idx = (blockIdx.x*256 + threadIdx.x)*4;
    if (idx >= n) return;
    float4 v = *(const float4*)(x + idx);
    ushort4 h, l;
    h.x = f2bf(v.x); l.x = f2bf(v.x - bf2f(h.x));
    h.y = f2bf(v.y); l.y = f2bf(v.y - bf2f(h.y));
    h.z = f2bf(v.z); l.z = f2bf(v.z - bf2f(h.z));
    h.w = f2bf(v.w); l.w = f2bf(v.w - bf2f(h.w));
    *(ushort4*)(hi + idx) = h;
    *(ushort4*)(lo + idx) = l;
}

__global__ __launch_bounds__(256)
void zero_kernel(float* p, int n){
    int i = blockIdx.x*256 + threadIdx.x;
    if (i < n) p[i] = 0.f;
}

// ------------- hi/lo split-bf16 MFMA GEMM: C[M,N] = A[M,K] @ B[N,K]^T -------
// 3-term (AhBh + AhBl + AlBh), 128x128 tile, BK=32, 256 thr, 64x64 wave tiles.
// Attention epilogue (avec != 0) emits s_src/s_dst PRE-SCALED by log2(e).
__global__ __launch_bounds__(256)
void gemm_hilo(const ushort_t* __restrict__ Ahi, const ushort_t* __restrict__ Alo,
               const ushort_t* __restrict__ Bhi, const ushort_t* __restrict__ Blo,
               const float* __restrict__ bias, float* __restrict__ outF,
               ushort_t* __restrict__ outHi, ushort_t* __restrict__ outLo,
               const float* __restrict__ avec, float* __restrict__ ssrc,
               float* __restrict__ sdst, int M, int N, int K)
{
    __shared__ ushort_t sA[2][2][128*32];
    __shared__ ushort_t sB[2][2][128*32];
    const int tid  = threadIdx.x;
    const int w    = tid >> 6, lane = tid & 63;
    const int l15  = lane & 15, l4 = lane >> 4;
    const int wr   = w >> 1, wcl = w & 1;
    const int m0   = blockIdx.y * 128, n0 = blockIdx.x * 128;

    f32x4 acc[4][4];
#pragma unroll
    for (int r = 0; r < 4; ++r)
#pragma unroll
        for (int t = 0; t < 4; ++t) acc[r][t] = (f32x4){0.f,0.f,0.f,0.f};

    auto stage = [&](int buf, int k0){
#pragma unroll
        for (int s = 0; s < 2; ++s) {
            const int rr = w*32 + s*16;
            const int gr = rr + (lane >> 2);
            const int gc = k0 + (lane & 3)*8;
            gload16(Ahi + (size_t)(m0+gr)*K + gc, &sA[buf][0][rr*32]);
            gload16(Alo + (size_t)(m0+gr)*K + gc, &sA[buf][1][rr*32]);
            int br = n0 + gr; if (br >= N) br = N-1;
            gload16(Bhi + (size_t)br*K + gc, &sB[buf][0][rr*32]);
            gload16(Blo + (size_t)br*K + gc, &sB[buf][1][rr*32]);
        }
    };

    stage(0, 0);
    int buf = 0;
    for (int k0 = 0; k0 < K; k0 += 32) {
        __syncthreads();
        if (k0 + 32 < K) stage(buf^1, k0 + 32);
        bf16x8 ah[4], al[4], bh[4], bl[4];
#pragma unroll
        for (int r = 0; r < 4; ++r) {
            const int off = (wr*64 + r*16 + l15)*32 + l4*8;
            ah[r] = *(const bf16x8*)&sA[buf][0][off];
            al[r] = *(const bf16x8*)&sA[buf][1][off];
        }
#pragma unroll
        for (int t = 0; t < 4; ++t) {
            const int off = (wcl*64 + t*16 + l15)*32 + l4*8;
            bh[t] = *(const bf16x8*)&sB[buf][0][off];
            bl[t] = *(const bf16x8*)&sB[buf][1][off];
        }
#pragma unroll
        for (int r = 0; r < 4; ++r)
#pragma unroll
            for (int t = 0; t < 4; ++t) {
                acc[r][t] = __builtin_amdgcn_mfma_f32_16x16x32_bf16(ah[r], bh[t], acc[r][t], 0,0,0);
                acc[r][t] = __builtin_amdgcn_mfma_f32_16x16x32_bf16(ah[r], bl[t], acc[r][t], 0,0,0);
                acc[r][t] = __builtin_amdgcn_mfma_f32_16x16x32_bf16(al[r], bh[t], acc[r][t], 0,0,0);
            }
        buf ^= 1;
    }

    const int hdr = m0 >> 8;     // head (gT GEMM: rows are head*HID+c)
    if (avec) {
        float as[4][4], ad[4][4];
#pragma unroll
        for (int r = 0; r < 4; ++r)
#pragma unroll
            for (int g = 0; g < 4; ++g) {
                const int aid = (m0 + wr*64 + r*16 + l4*4 + g) & (HID-1);
                as[r][g] = avec[hdr*2*HID + aid];
                ad[r][g] = avec[hdr*2*HID + HID + aid];
            }
#pragma unroll
        for (int t = 0; t < 4; ++t) {
            float ps = 0.f, pd = 0.f;
#pragma unroll
            for (int r = 0; r < 4; ++r)
#pragma unroll
                for (int g = 0; g < 4; ++g) {
                    ps += acc[r][t][g] * as[r][g];
                    pd += acc[r][t][g] * ad[r][g];
                }
            ps += __shfl_xor(ps, 16); ps += __shfl_xor(ps, 32);
            pd += __shfl_xor(pd, 16); pd += __shfl_xor(pd, 32);
            if (lane < 16) {
                const int n = n0 + wcl*64 + t*16 + lane;
                atomicAdd(&ssrc[(size_t)hdr*N_NODES + n], ps * LOG2E);
                atomicAdd(&sdst[(size_t)hdr*N_NODES + n], pd * LOG2E);
            }
        }
    }

#pragma unroll
    for (int r = 0; r < 4; ++r)
#pragma unroll
        for (int t = 0; t < 4; ++t)
#pragma unroll
            for (int g = 0; g < 4; ++g) {
                const int row = m0 + wr*64 + r*16 + l4*4 + g;
                const int col = n0 + wcl*64 + t*16 + l15;
                if (col < N) {
                    float v = acc[r][t][g] + (bias ? bias[col] : 0.f);
                    if (outF) outF[(size_t)row*N + col] = v;
                    else {
                        ushort_t hv = f2bf(v);
                        outHi[(size_t)row*N + col] = hv;
                        if (outLo) outLo[(size_t)row*N + col] = f2bf(v - bf2f(hv));
                    }
                }
            }
}

// ----- rowC[h][i] = (m + logZ) in log2 domain; inputs pre-scaled by log2e ---
__global__ __launch_bounds__(256)
void rowmz_kernel(const unsigned* __restrict__ maskJ, const float* __restrict__ s_src,
                  const float* __restrict__ s_dst, float* __restrict__ rowC)
{
    const int i   = blockIdx.x;
    const int tid = threadIdx.x;
    const int w   = tid & 127;
    const int hp  = tid >> 7;
    const unsigned bits = maskJ[(size_t)i*NWORDS + w];
    const float* sd0 = s_dst + (size_t)(2*hp  )*N_NODES + w*32;
    const float* sd1 = s_dst + (size_t)(2*hp+1)*N_NODES + w*32;

    float md0 = -INFINITY, md1 = -INFINITY;
#pragma unroll
    for (int k = 0; k < 8; ++k) {
        float4 a4 = *(const float4*)(sd0 + k*4);
        float4 b4 = *(const float4*)(sd1 + k*4);
        md0 = fmaxf(md0, ((bits>>(4*k+0))&1) ? a4.x : -INFINITY);
        md0 = fmaxf(md0, ((bits>>(4*k+1))&1) ? a4.y : -INFINITY);
        md0 = fmaxf(md0, ((bits>>(4*k+2))&1) ? a4.z : -INFINITY);
        md0 = fmaxf(md0, ((bits>>(4*k+3))&1) ? a4.w : -INFINITY);
        md1 = fmaxf(md1, ((bits>>(4*k+0))&1) ? b4.x : -INFINITY);
        md1 = fmaxf(md1, ((bits>>(4*k+1))&1) ? b4.y : -INFINITY);
        md1 = fmaxf(md1, ((bits>>(4*k+2))&1) ? b4.z : -INFINITY);
        md1 = fmaxf(md1, ((bits>>(4*k+3))&1) ? b4.w : -INFINITY);
    }
#pragma unroll
    for (int off = 32; off; off >>= 1) {
        md0 = fmaxf(md0, __shfl_down(md0, off));
        md1 = fmaxf(md1, __shfl_down(md1, off));
    }
    __shared__ float Wr[4][2];
    const int wv = tid >> 6;
    if ((tid & 63) == 0) { Wr[wv][0] = md0; Wr[wv][1] = md1; }
    __syncthreads();
    const float ss0 = s_src[(size_t)(2*hp  )*N_NODES + i];
    const float ss1 = s_src[(size_t)(2*hp+1)*N_NODES + i];
    const float t0 = ss0 + fmaxf(Wr[hp*2][0], Wr[hp*2+1][0]);
    const float t1 = ss1 + fmaxf(Wr[hp*2][1], Wr[hp*2+1][1]);
    const float M0 = fmaxf(t0, ALPHA*t0);
    const float M1 = fmaxf(t1, ALPHA*t1);

    float z0 = 0.f, z1 = 0.f;
#pragma unroll
    for (int k = 0; k < 8; ++k) {
        float4 a4 = *(const float4*)(sd0 + k*4);
        float4 b4 = *(const float4*)(sd1 + k*4);
#pragma unroll
        for (int q = 0; q < 4; ++q) {
            float ea = ss0 + ((const float*)&a4)[q];
            float eb = ss1 + ((const float*)&b4)[q];
            z0 += ((bits>>(4*k+q))&1) ? fexp2(fmaxf(ea, ALPHA*ea) - M0) : 0.f;
            z1 += ((bits>>(4*k+q))&1) ? fexp2(fmaxf(eb, ALPHA*eb) - M1) : 0.f;
        }
    }
#pragma unroll
    for (int off = 32; off; off >>= 1) {
        z0 += __shfl_down(z0, off);
        z1 += __shfl_down(z1, off);
    }
    __syncthreads();
    if ((tid & 63) == 0) { Wr[wv][0] = z0; Wr[wv][1] = z1; }
    __syncthreads();
    if ((tid & 127) == 0) {
        rowC[(size_t)(2*hp  )*N_NODES + i] = M0 + __log2f(Wr[hp*2][0] + Wr[hp*2+1][0]);
        rowC[(size_t)(2*hp+1)*N_NODES + i] = M1 + __log2f(Wr[hp*2][1] + Wr[hp*2+1][1]);
    }
}

// -------- attg: part[i][h*HID+c] = sum_{j in half} P(i,j) * g[j][c] ---------
// P = 2^(max(t, .2t) - Cl), t = ssl_i + sdl_j  (all pre-scaled by log2 e).
// 256 thr / 4 waves; block tile 128 i x 128 c; wave = 32 i x 128 c -> zero
// P redundancy. gsT swizzled (slot ^= (c>>1)&3) for conflict-free b128 reads.
__global__ __launch_bounds__(256)
void attg_kernel(const ushort_t* __restrict__ gThi, const unsigned* __restrict__ maskJ,
                 const float* __restrict__ ssl, const float* __restrict__ Cl,
                 const float* __restrict__ sdl, float* __restrict__ part0,
                 float* __restrict__ part1)
{
    __shared__ ushort_t gsT[2][128*32];
    const int tid = threadIdx.x;
    const int w   = tid >> 6, lane = tid & 63;
    const int l15 = lane & 15, l4 = lane >> 4;
    const int h   = blockIdx.y >> 1;
    const int cs0 = (blockIdx.y & 1) * 128;
    const int i0  = blockIdx.x * 128;
    const int z   = blockIdx.z;
    const int jbase = z * (N_NODES/2);
    const size_t hN = (size_t)h * N_NODES;

    const int r0 = i0 + w*32 + l15;
    const int r1 = r0 + 16;
    const float ssl0 = ssl[hN + r0], ssl1 = ssl[hN + r1];
    const float Cl0  = Cl [hN + r0], Cl1  = Cl [hN + r1];

    f32x4 acc[2][8];
#pragma unroll
    for (int r = 0; r < 2; ++r)
#pragma unroll
        for (int t = 0; t < 8; ++t) acc[r][t] = (f32x4){0.f,0.f,0.f,0.f};

    auto stage = [&](int buf, int j0){
#pragma unroll
        for (int s = 0; s < 2; ++s) {
            const int c    = w*32 + s*16 + (lane >> 2);
            const int slot = (lane & 3) ^ ((c >> 1) & 3);
            gload16(gThi + (size_t)(h*HID + cs0 + c)*N_NODES + j0 + slot*8,
                    &gsT[buf][(w*32 + s*16)*32]);
        }
    };

    stage(0, jbase);
    unsigned mwA = maskJ[(size_t)r0*NWORDS + (jbase>>5)];
    unsigned mwB = maskJ[(size_t)r1*NWORDS + (jbase>>5)];
    float4 sdA = *(const float4*)(sdl + hN + jbase + l4*8);
    float4 sdB = *(const float4*)(sdl + hN + jbase + l4*8 + 4);

    int buf = 0;
    for (int tt = 0; tt < 64; ++tt) {
        const int j0 = jbase + tt*32;
        __syncthreads();
        unsigned nmwA = 0, nmwB = 0; float4 nsdA = sdA, nsdB = sdB;
        if (tt + 1 < 64) {
            stage(buf^1, j0 + 32);
            nmwA = maskJ[(size_t)r0*NWORDS + ((j0+32)>>5)];
            nmwB = maskJ[(size_t)r1*NWORDS + ((j0+32)>>5)];
            nsdA = *(const float4*)(sdl + hN + j0 + 32 + l4*8);
            nsdB = *(const float4*)(sdl + hN + j0 + 32 + l4*8 + 4);
        }

        const float sdv[8] = {sdA.x,sdA.y,sdA.z,sdA.w,sdB.x,sdB.y,sdB.z,sdB.w};
        bf16x8 af0, af1;
#pragma unroll
        for (int q = 0; q < 8; ++q) {
            const float t0 = ssl0 + sdv[q];
            const float t1 = ssl1 + sdv[q];
            float p0 = fexp2(fmaxf(t0, ALPHA*t0) - Cl0);
            float p1 = fexp2(fmaxf(t1, ALPHA*t1) - Cl1);
            const int bit = l4*8 + q;
            p0 = ((mwA >> bit) & 1u) ? p0 : 0.f;
            p1 = ((mwB >> bit) & 1u) ? p1 : 0.f;
            af0[q] = (short)f2bf(p0);
            af1[q] = (short)f2bf(p1);
        }
#pragma unroll
        for (int t = 0; t < 8; ++t) {
            const int cloc = t*16 + l15;
            const int slot = l4 ^ ((cloc >> 1) & 3);
            const bf16x8 bfr = *(const bf16x8*)&gsT[buf][cloc*32 + slot*8];
            acc[0][t] = __builtin_amdgcn_mfma_f32_16x16x32_bf16(af0, bfr, acc[0][t], 0,0,0);
            acc[1][t] = __builtin_amdgcn_mfma_f32_16x16x32_bf16(af1, bfr, acc[1][t], 0,0,0);
        }
        mwA = nmwA; mwB = nmwB; sdA = nsdA; sdB = nsdB;
        buf ^= 1;
    }

    float* dst = z ? part1 : part0;
#pragma unroll
    for (int r = 0; r < 2; ++r)
#pragma unroll
        for (int t = 0; t < 8; ++t)
#pragma unroll
            for (int g = 0; g < 4; ++g) {
                const int row = i0 + w*32 + r*16 + l4*4 + g;
                const int col = h*HID + cs0 + t*16 + l15;
                dst[(size_t)row*GCOLS + col] = acc[r][t][g];
            }
}

// ---------- hcat (hi/lo bf16) = elu(part0 + part1) --------------------------
__global__ __launch_bounds__(256)
void reduce_elu2(const float* __restrict__ p0, const float* __restrict__ p1,
                 ushort_t* __restrict__ hi, ushort_t* __restrict__ lo)
{
    const size_t idx = ((size_t)blockIdx.x*256 + threadIdx.x)*4;
    float4 a = *(const float4*)(p0 + idx);
    float4 b = *(const float4*)(p1 + idx);
    float v0 = elu_f(a.x + b.x), v1 = elu_f(a.y + b.y);
    float v2 = elu_f(a.z + b.z), v3 = elu_f(a.w + b.w);
    ushort4 h, l;
    h.x = f2bf(v0); l.x = f2bf(v0 - bf2f(h.x));
    h.y = f2bf(v1); l.y = f2bf(v1 - bf2f(h.y));
    h.z = f2bf(v2); l.z = f2bf(v2 - bf2f(h.z));
    h.w = f2bf(v3); l.w = f2bf(v3 - bf2f(h.w));
    *(ushort4*)(hi + idx) = h;
    *(ushort4*)(lo + idx) = l;
}

extern "C" void kernel_launch(void* const* d_in, const int* in_sizes, int n_in,
                              void* d_out, int out_size, void* d_ws, size_t ws_size,
                              hipStream_t stream)
{
    const float* label = (const float*)d_in[0];
    const float* W1    = (const float*)d_in[1];
    const float* a1    = (const float*)d_in[2];
    const float* W2    = (const float*)d_in[3];
    const float* a2    = (const float*)d_in[4];
    const float* out_w = (const float*)d_in[5];
    const float* out_b = (const float*)d_in[6];
    const float* out2_w= (const float*)d_in[7];
    const float* out2_b= (const float*)d_in[8];
    const int*   adj   = (const int*)d_in[9];
    float* out = (float*)d_out;

    char* p = (char*)d_ws;
    auto alloc = [&](size_t bytes){ char* r = p; p += (bytes + 255) & ~(size_t)255; return r; };
    float*    part0 = (float*)   alloc((size_t)N_NODES*GCOLS*4);      // 16 MB
    float*    part1 = (float*)   alloc((size_t)N_NODES*GCOLS*4);      // 16 MB
    ushort_t* gThi  = (ushort_t*)alloc((size_t)GCOLS*N_NODES*2);      // 8 MB
    ushort_t* hchi  = (ushort_t*)alloc((size_t)N_NODES*GCOLS*2);      // 8 MB
    ushort_t* hclo  = (ushort_t*)alloc((size_t)N_NODES*GCOLS*2);      // 8 MB
    ushort_t* xlhi  = (ushort_t*)alloc((size_t)N_NODES*IN_DIM*2);     // 6 MB (label, then x1)
    ushort_t* xllo  = (ushort_t*)alloc((size_t)N_NODES*IN_DIM*2);     // 6 MB
    ushort_t* w1hi  = (ushort_t*)alloc((size_t)GCOLS*IN_DIM*2);
    ushort_t* w1lo  = (ushort_t*)alloc((size_t)GCOLS*IN_DIM*2);
    ushort_t* w2hi  = (ushort_t*)alloc((size_t)GCOLS*IN_DIM*2);
    ushort_t* w2lo  = (ushort_t*)alloc((size_t)GCOLS*IN_DIM*2);
    ushort_t* owhi  = (ushort_t*)alloc((size_t)IN_DIM*GCOLS*2);
    ushort_t* owlo  = (ushort_t*)alloc((size_t)IN_DIM*GCOLS*2);
    ushort_t* o2hi  = (ushort_t*)alloc((size_t)OUT_DIM*GCOLS*2);
    ushort_t* o2lo  = (ushort_t*)alloc((size_t)OUT_DIM*GCOLS*2);
    unsigned* maskJ = (unsigned*)alloc((size_t)N_NODES*NWORDS*4);     // 2 MB
    float*    ssrc  = (float*)   alloc((size_t)HEADS*N_NODES*4);
    float*    sdst  = (float*)   alloc((size_t)HEADS*N_NODES*4);
    float*    rC    = (float*)   alloc((size_t)HEADS*N_NODES*4);

    pack_kernel<<<N_NODES/4, 256, 0, stream>>>(adj, maskJ);
    cvt_hilo<<<(N_NODES*IN_DIM)/1024, 256, 0, stream>>>(label, xlhi, xllo, N_NODES*IN_DIM);
    cvt_hilo<<<(GCOLS*IN_DIM)/1024, 256, 0, stream>>>(W1, w1hi, w1lo, GCOLS*IN_DIM);
    cvt_hilo<<<(GCOLS*IN_DIM)/1024, 256, 0, stream>>>(W2, w2hi, w2lo, GCOLS*IN_DIM);
    cvt_hilo<<<(IN_DIM*GCOLS)/1024, 256, 0, stream>>>(out_w, owhi, owlo, IN_DIM*GCOLS);
    cvt_hilo<<<(OUT_DIM*GCOLS)/1024, 256, 0, stream>>>(out2_w, o2hi, o2lo, OUT_DIM*GCOLS);

    auto layer = [&](const ushort_t* Whi, const ushort_t* Wlo, const float* avec,
                     const ushort_t* hhi, const ushort_t* hlo, int K) {
        zero_kernel<<<(2*HEADS*N_NODES)/256, 256, 0, stream>>>(ssrc, 2*HEADS*N_NODES);
        // gT[c][j] (+ scaled s_src/s_dst atomics):  gT = W @ h^T
        gemm_hilo<<<dim3(N_NODES/128, GCOLS/128), 256, 0, stream>>>(
            Whi, Wlo, hhi, hlo, nullptr, nullptr, gThi, nullptr,
            avec, ssrc, sdst, GCOLS, N_NODES, K);
        rowmz_kernel<<<N_NODES, 256, 0, stream>>>(maskJ, ssrc, sdst, rC);
        attg_kernel<<<dim3(N_NODES/128, HEADS*2, 2), 256, 0, stream>>>(
            gThi, maskJ, ssrc, rC, sdst, part0, part1);
        reduce_elu2<<<(N_NODES*GCOLS)/1024, 256, 0, stream>>>(part0, part1, hchi, hclo);
    };

    layer(w1hi, w1lo, a1, xlhi, xllo, IN_DIM);
    // x1 = hcat @ out_w^T + out_b  -> split bf16 (overwrites label slot)
    gemm_hilo<<<dim3(IN_DIM/128, N_NODES/128), 256, 0, stream>>>(
        hchi, hclo, owhi, owlo, out_b, nullptr, xlhi, xllo,
        nullptr, nullptr, nullptr, N_NODES, IN_DIM, GCOLS);
    layer(w2hi, w2lo, a2, xlhi, xllo, IN_DIM);
    // out = hcat @ out2_w^T + out2_b  (fp32, N=32 guarded)
    gemm_hilo<<<dim3(1, N_NODES/128), 256, 0, stream>>>(
        hchi, hclo, o2hi, o2lo, out2_b, out, nullptr, nullptr,
        nullptr, nullptr, nullptr, N_NODES, OUT_DIM, GCOLS);
}

// Round 7
// 496.318 us; speedup vs baseline: 5.0581x; 1.3532x over previous
//
#include <hip/hip_runtime.h>
#include <hip/hip_bf16.h>
#include <math.h>

#define N_NODES 4096
#define IN_DIM  768
#define HID     256
#define HEADS   4
#define OUT_DIM 32
#define ALPHA   0.2f
#define GCOLS   (HEADS*HID)   // 1024
#define NWORDS  (N_NODES/32)  // 128 mask words per row
#define LOG2E   1.4426950408889634f

typedef unsigned short ushort_t;
typedef short bf16x8 __attribute__((ext_vector_type(8)));
typedef float f32x4 __attribute__((ext_vector_type(4)));

__device__ __forceinline__ float elu_f(float x){ return x > 0.f ? x : expm1f(x); }

__device__ __forceinline__ float fexp2(float x){
#if __has_builtin(__builtin_amdgcn_exp2f)
    return __builtin_amdgcn_exp2f(x);
#else
    return exp2f(x);
#endif
}

__device__ __forceinline__ ushort_t f2bf(float x){
    unsigned u = __float_as_uint(x);
    return (ushort_t)((u + 0x7FFFu + ((u >> 16) & 1u)) >> 16);
}
__device__ __forceinline__ float bf2f(ushort_t h){
    return __uint_as_float(((unsigned)h) << 16);
}
__device__ __forceinline__ void gload16(const void* g, void* l){
    __builtin_amdgcn_global_load_lds((const __attribute__((address_space(1))) void*)(g),
                                     (__attribute__((address_space(3))) void*)(l), 16, 0, 0);
}

// ---------------- pack adj -> bitmask maskJ[i][jword] -----------------------
__global__ __launch_bounds__(256)
void pack_kernel(const int* __restrict__ adj, unsigned* __restrict__ maskJ)
{
    const int w    = threadIdx.x >> 6;
    const int lane = threadIdx.x & 63;
    const int i    = blockIdx.x * 4 + w;
    const int* arow = adj + (size_t)i * N_NODES;
    for (int jt = 0; jt < 64; ++jt) {
        unsigned long long b = __ballot(arow[jt*64 + lane] != 0);
        if (lane == 0) {
            maskJ[(size_t)i*NWORDS + jt*2    ] = (unsigned)b;
            maskJ[(size_t)i*NWORDS + jt*2 + 1] = (unsigned)(b >> 32);
        }
    }
}

// ---------------- fp32 -> bf16 hi/lo split ----------------------------------
__global__ __launch_bounds__(256)
void cvt_hilo(const float* __restrict__ x, ushort_t* __restrict__ hi,
              ushort_t* __restrict__ lo, int n)
{
    const int idx = (blockIdx.x*256 + threadIdx.x)*4;
    if (idx >= n) return;
    float4 v = *(const float4*)(x + idx);
    ushort4 h, l;
    h.x = f2bf(v.x); l.x = f2bf(v.x - bf2f(h.x));
    h.y = f2bf(v.y); l.y = f2bf(v.y - bf2f(h.y));
    h.z = f2bf(v.z); l.z = f2bf(v.z - bf2f(h.z));
    h.w = f2bf(v.w); l.w = f2bf(v.w - bf2f(h.w));
    *(ushort4*)(hi + idx) = h;
    *(ushort4*)(lo + idx) = l;
}

__global__ __launch_bounds__(256)
void zero_kernel(float* p, int n){
    int i = blockIdx.x*256 + threadIdx.x;
    if (i < n) p[i] = 0.f;
}

// ------------- hi/lo split-bf16 MFMA GEMM: C[M,N] = A[M,K] @ B[N,K]^T -------
// 3-term (AhBh + AhBl + AlBh), 128x128 tile, BK=32, 256 thr, 64x64 wave tiles.
// Attention epilogue (avec != 0) emits s_src/s_dst PRE-SCALED by log2(e).
__global__ __launch_bounds__(256)
void gemm_hilo(const ushort_t* __restrict__ Ahi, const ushort_t* __restrict__ Alo,
               const ushort_t* __restrict__ Bhi, const ushort_t* __restrict__ Blo,
               const float* __restrict__ bias, float* __restrict__ outF,
               ushort_t* __restrict__ outHi, ushort_t* __restrict__ outLo,
               const float* __restrict__ avec, float* __restrict__ ssrc,
               float* __restrict__ sdst, int M, int N, int K)
{
    __shared__ ushort_t sA[2][2][128*32];
    __shared__ ushort_t sB[2][2][128*32];
    const int tid  = threadIdx.x;
    const int w    = tid >> 6, lane = tid & 63;
    const int l15  = lane & 15, l4 = lane >> 4;
    const int wr   = w >> 1, wcl = w & 1;
    const int m0   = blockIdx.y * 128, n0 = blockIdx.x * 128;

    f32x4 acc[4][4];
#pragma unroll
    for (int r = 0; r < 4; ++r)
#pragma unroll
        for (int t = 0; t < 4; ++t) acc[r][t] = (f32x4){0.f,0.f,0.f,0.f};

    auto stage = [&](int buf, int k0){
#pragma unroll
        for (int s = 0; s < 2; ++s) {
            const int rr = w*32 + s*16;
            const int gr = rr + (lane >> 2);
            const int gc = k0 + (lane & 3)*8;
            gload16(Ahi + (size_t)(m0+gr)*K + gc, &sA[buf][0][rr*32]);
            gload16(Alo + (size_t)(m0+gr)*K + gc, &sA[buf][1][rr*32]);
            int br = n0 + gr; if (br >= N) br = N-1;
            gload16(Bhi + (size_t)br*K + gc, &sB[buf][0][rr*32]);
            gload16(Blo + (size_t)br*K + gc, &sB[buf][1][rr*32]);
        }
    };

    stage(0, 0);
    int buf = 0;
    for (int k0 = 0; k0 < K; k0 += 32) {
        __syncthreads();
        if (k0 + 32 < K) stage(buf^1, k0 + 32);
        bf16x8 ah[4], al[4], bh[4], bl[4];
#pragma unroll
        for (int r = 0; r < 4; ++r) {
            const int off = (wr*64 + r*16 + l15)*32 + l4*8;
            ah[r] = *(const bf16x8*)&sA[buf][0][off];
            al[r] = *(const bf16x8*)&sA[buf][1][off];
        }
#pragma unroll
        for (int t = 0; t < 4; ++t) {
            const int off = (wcl*64 + t*16 + l15)*32 + l4*8;
            bh[t] = *(const bf16x8*)&sB[buf][0][off];
            bl[t] = *(const bf16x8*)&sB[buf][1][off];
        }
#pragma unroll
        for (int r = 0; r < 4; ++r)
#pragma unroll
            for (int t = 0; t < 4; ++t) {
                acc[r][t] = __builtin_amdgcn_mfma_f32_16x16x32_bf16(ah[r], bh[t], acc[r][t], 0,0,0);
                acc[r][t] = __builtin_amdgcn_mfma_f32_16x16x32_bf16(ah[r], bl[t], acc[r][t], 0,0,0);
                acc[r][t] = __builtin_amdgcn_mfma_f32_16x16x32_bf16(al[r], bh[t], acc[r][t], 0,0,0);
            }
        buf ^= 1;
    }

    const int hdr = m0 >> 8;     // head (gT GEMM: rows are head*HID+c)
    if (avec) {
        float as[4][4], ad[4][4];
#pragma unroll
        for (int r = 0; r < 4; ++r)
#pragma unroll
            for (int g = 0; g < 4; ++g) {
                const int aid = (m0 + wr*64 + r*16 + l4*4 + g) & (HID-1);
                as[r][g] = avec[hdr*2*HID + aid];
                ad[r][g] = avec[hdr*2*HID + HID + aid];
            }
#pragma unroll
        for (int t = 0; t < 4; ++t) {
            float ps = 0.f, pd = 0.f;
#pragma unroll
            for (int r = 0; r < 4; ++r)
#pragma unroll
                for (int g = 0; g < 4; ++g) {
                    ps += acc[r][t][g] * as[r][g];
                    pd += acc[r][t][g] * ad[r][g];
                }
            ps += __shfl_xor(ps, 16); ps += __shfl_xor(ps, 32);
            pd += __shfl_xor(pd, 16); pd += __shfl_xor(pd, 32);
            if (lane < 16) {
                const int n = n0 + wcl*64 + t*16 + lane;
                atomicAdd(&ssrc[(size_t)hdr*N_NODES + n], ps * LOG2E);
                atomicAdd(&sdst[(size_t)hdr*N_NODES + n], pd * LOG2E);
            }
        }
    }

#pragma unroll
    for (int r = 0; r < 4; ++r)
#pragma unroll
        for (int t = 0; t < 4; ++t)
#pragma unroll
            for (int g = 0; g < 4; ++g) {
                const int row = m0 + wr*64 + r*16 + l4*4 + g;
                const int col = n0 + wcl*64 + t*16 + l15;
                if (col < N) {
                    float v = acc[r][t][g] + (bias ? bias[col] : 0.f);
                    if (outF) outF[(size_t)row*N + col] = v;
                    else {
                        ushort_t hv = f2bf(v);
                        outHi[(size_t)row*N + col] = hv;
                        if (outLo) outLo[(size_t)row*N + col] = f2bf(v - bf2f(hv));
                    }
                }
            }
}

// ----------- maxsd[h] = max_j sdl[h][j]  (unmasked upper bound) -------------
__global__ __launch_bounds__(256)
void maxsd_kernel(const float* __restrict__ sdl, float* __restrict__ maxsd)
{
    const int h   = blockIdx.x;
    const int tid = threadIdx.x;
    const float* p = sdl + (size_t)h * N_NODES;
    float m = -INFINITY;
#pragma unroll
    for (int k = 0; k < 4; ++k) {
        float4 v = *(const float4*)(p + (k*256 + tid)*4);
        m = fmaxf(m, fmaxf(fmaxf(v.x, v.y), fmaxf(v.z, v.w)));
    }
#pragma unroll
    for (int off = 32; off; off >>= 1) m = fmaxf(m, __shfl_down(m, off));
    __shared__ float wm[4];
    if ((tid & 63) == 0) wm[tid >> 6] = m;
    __syncthreads();
    if (tid == 0)
        maxsd[h] = fmaxf(fmaxf(wm[0], wm[1]), fmaxf(wm[2], wm[3]));
}

// -------- attg: part[i][c] = sum_j P~(i,j) g[j][c];  zp[i] = sum_j P~(i,j) --
// P~ = 2^(max(t,.2t) - M_i), t = ssl_i + sdl_j, M_i = max(u,.2u), u=ssl_i+maxsd.
// 256 thr / 4 waves; block tile 128 i x 128 c; wave = 32 i x 128 c.
// Z via ones-vector MFMA into acc_z; written only by cs0==0 blocks.
__global__ __launch_bounds__(256)
void attg_kernel(const ushort_t* __restrict__ gThi, const unsigned* __restrict__ maskJ,
                 const float* __restrict__ ssl, const float* __restrict__ maxsd,
                 const float* __restrict__ sdl, float* __restrict__ part0,
                 float* __restrict__ part1, float* __restrict__ zp)
{
    __shared__ ushort_t gsT[2][128*32];
    const int tid = threadIdx.x;
    const int w   = tid >> 6, lane = tid & 63;
    const int l15 = lane & 15, l4 = lane >> 4;
    const int h   = blockIdx.y >> 1;
    const int cs0 = (blockIdx.y & 1) * 128;
    const int i0  = blockIdx.x * 128;
    const int z   = blockIdx.z;
    const int jbase = z * (N_NODES/2);
    const size_t hN = (size_t)h * N_NODES;

    const int r0 = i0 + w*32 + l15;
    const int r1 = r0 + 16;
    const float msd  = maxsd[h];
    const float ssl0 = ssl[hN + r0], ssl1 = ssl[hN + r1];
    const float u0 = ssl0 + msd, u1 = ssl1 + msd;
    const float Cl0 = fmaxf(u0, ALPHA*u0);
    const float Cl1 = fmaxf(u1, ALPHA*u1);

    f32x4 acc[2][8];
#pragma unroll
    for (int r = 0; r < 2; ++r)
#pragma unroll
        for (int t = 0; t < 8; ++t) acc[r][t] = (f32x4){0.f,0.f,0.f,0.f};
    f32x4 accz[2];
    accz[0] = (f32x4){0.f,0.f,0.f,0.f};
    accz[1] = (f32x4){0.f,0.f,0.f,0.f};
    bf16x8 ones;
#pragma unroll
    for (int q = 0; q < 8; ++q) ones[q] = (short)0x3F80;

    auto stage = [&](int buf, int j0){
#pragma unroll
        for (int s = 0; s < 2; ++s) {
            const int c    = w*32 + s*16 + (lane >> 2);
            const int slot = (lane & 3) ^ ((c >> 1) & 3);
            gload16(gThi + (size_t)(h*HID + cs0 + c)*N_NODES + j0 + slot*8,
                    &gsT[buf][(w*32 + s*16)*32]);
        }
    };

    stage(0, jbase);
    unsigned mwA = maskJ[(size_t)r0*NWORDS + (jbase>>5)];
    unsigned mwB = maskJ[(size_t)r1*NWORDS + (jbase>>5)];
    float4 sdA = *(const float4*)(sdl + hN + jbase + l4*8);
    float4 sdB = *(const float4*)(sdl + hN + jbase + l4*8 + 4);

    int buf = 0;
    for (int tt = 0; tt < 64; ++tt) {
        const int j0 = jbase + tt*32;
        __syncthreads();
        unsigned nmwA = 0, nmwB = 0; float4 nsdA = sdA, nsdB = sdB;
        if (tt + 1 < 64) {
            stage(buf^1, j0 + 32);
            nmwA = maskJ[(size_t)r0*NWORDS + ((j0+32)>>5)];
            nmwB = maskJ[(size_t)r1*NWORDS + ((j0+32)>>5)];
            nsdA = *(const float4*)(sdl + hN + j0 + 32 + l4*8);
            nsdB = *(const float4*)(sdl + hN + j0 + 32 + l4*8 + 4);
        }

        const float sdv[8] = {sdA.x,sdA.y,sdA.z,sdA.w,sdB.x,sdB.y,sdB.z,sdB.w};
        bf16x8 af0, af1;
#pragma unroll
        for (int q = 0; q < 8; ++q) {
            const float t0 = ssl0 + sdv[q];
            const float t1 = ssl1 + sdv[q];
            float p0 = fexp2(fmaxf(t0, ALPHA*t0) - Cl0);
            float p1 = fexp2(fmaxf(t1, ALPHA*t1) - Cl1);
            const int bit = l4*8 + q;
            p0 = ((mwA >> bit) & 1u) ? p0 : 0.f;
            p1 = ((mwB >> bit) & 1u) ? p1 : 0.f;
            af0[q] = (short)f2bf(p0);
            af1[q] = (short)f2bf(p1);
        }
#pragma unroll
        for (int t = 0; t < 8; ++t) {
            const int cloc = t*16 + l15;
            const int slot = l4 ^ ((cloc >> 1) & 3);
            const bf16x8 bfr = *(const bf16x8*)&gsT[buf][cloc*32 + slot*8];
            acc[0][t] = __builtin_amdgcn_mfma_f32_16x16x32_bf16(af0, bfr, acc[0][t], 0,0,0);
            acc[1][t] = __builtin_amdgcn_mfma_f32_16x16x32_bf16(af1, bfr, acc[1][t], 0,0,0);
        }
        accz[0] = __builtin_amdgcn_mfma_f32_16x16x32_bf16(af0, ones, accz[0], 0,0,0);
        accz[1] = __builtin_amdgcn_mfma_f32_16x16x32_bf16(af1, ones, accz[1], 0,0,0);
        mwA = nmwA; mwB = nmwB; sdA = nsdA; sdB = nsdB;
        buf ^= 1;
    }

    float* dst = z ? part1 : part0;
#pragma unroll
    for (int r = 0; r < 2; ++r)
#pragma unroll
        for (int t = 0; t < 8; ++t)
#pragma unroll
            for (int g = 0; g < 4; ++g) {
                const int row = i0 + w*32 + r*16 + l4*4 + g;
                const int col = h*HID + cs0 + t*16 + l15;
                dst[(size_t)row*GCOLS + col] = acc[r][t][g];
            }
    if (cs0 == 0 && l15 == 0) {
        float* zrow = zp + (size_t)(h*2 + z)*N_NODES + i0 + w*32;
#pragma unroll
        for (int r = 0; r < 2; ++r)
#pragma unroll
            for (int g = 0; g < 4; ++g)
                zrow[r*16 + l4*4 + g] = accz[r][g];
    }
}

// ---------- hcat (hi/lo bf16) = elu((part0+part1)/Z) ------------------------
__global__ __launch_bounds__(256)
void reduce_elu2(const float* __restrict__ p0, const float* __restrict__ p1,
                 const float* __restrict__ zp,
                 ushort_t* __restrict__ hi, ushort_t* __restrict__ lo)
{
    const int gid = blockIdx.x*256 + threadIdx.x;   // one float4
    const int row = gid >> 8;                        // GCOLS/4 = 256 groups/row
    const int c4  = (gid & 255) * 4;
    const int h   = c4 >> 8;
    const float zt = zp[(size_t)(h*2  )*N_NODES + row]
                   + zp[(size_t)(h*2+1)*N_NODES + row];
    const float inv = 1.f / zt;
    const size_t idx = (size_t)row*GCOLS + c4;
    float4 a = *(const float4*)(p0 + idx);
    float4 b = *(const float4*)(p1 + idx);
    float v0 = elu_f((a.x + b.x)*inv), v1 = elu_f((a.y + b.y)*inv);
    float v2 = elu_f((a.z + b.z)*inv), v3 = elu_f((a.w + b.w)*inv);
    ushort4 hh, ll;
    hh.x = f2bf(v0); ll.x = f2bf(v0 - bf2f(hh.x));
    hh.y = f2bf(v1); ll.y = f2bf(v1 - bf2f(hh.y));
    hh.z = f2bf(v2); ll.z = f2bf(v2 - bf2f(hh.z));
    hh.w = f2bf(v3); ll.w = f2bf(v3 - bf2f(hh.w));
    *(ushort4*)(hi + idx) = hh;
    *(ushort4*)(lo + idx) = ll;
}

extern "C" void kernel_launch(void* const* d_in, const int* in_sizes, int n_in,
                              void* d_out, int out_size, void* d_ws, size_t ws_size,
                              hipStream_t stream)
{
    const float* label = (const float*)d_in[0];
    const float* W1    = (const float*)d_in[1];
    const float* a1    = (const float*)d_in[2];
    const float* W2    = (const float*)d_in[3];
    const float* a2    = (const float*)d_in[4];
    const float* out_w = (const float*)d_in[5];
    const float* out_b = (const float*)d_in[6];
    const float* out2_w= (const float*)d_in[7];
    const float* out2_b= (const float*)d_in[8];
    const int*   adj   = (const int*)d_in[9];
    float* out = (float*)d_out;

    char* p = (char*)d_ws;
    auto alloc = [&](size_t bytes){ char* r = p; p += (bytes + 255) & ~(size_t)255; return r; };
    float*    part0 = (float*)   alloc((size_t)N_NODES*GCOLS*4);      // 16 MB
    float*    part1 = (float*)   alloc((size_t)N_NODES*GCOLS*4);      // 16 MB
    ushort_t* gThi  = (ushort_t*)alloc((size_t)GCOLS*N_NODES*2);      // 8 MB
    ushort_t* hchi  = (ushort_t*)alloc((size_t)N_NODES*GCOLS*2);      // 8 MB
    ushort_t* hclo  = (ushort_t*)alloc((size_t)N_NODES*GCOLS*2);      // 8 MB
    ushort_t* xlhi  = (ushort_t*)alloc((size_t)N_NODES*IN_DIM*2);     // 6 MB (label, then x1)
    ushort_t* xllo  = (ushort_t*)alloc((size_t)N_NODES*IN_DIM*2);     // 6 MB
    ushort_t* w1hi  = (ushort_t*)alloc((size_t)GCOLS*IN_DIM*2);
    ushort_t* w1lo  = (ushort_t*)alloc((size_t)GCOLS*IN_DIM*2);
    ushort_t* w2hi  = (ushort_t*)alloc((size_t)GCOLS*IN_DIM*2);
    ushort_t* w2lo  = (ushort_t*)alloc((size_t)GCOLS*IN_DIM*2);
    ushort_t* owhi  = (ushort_t*)alloc((size_t)IN_DIM*GCOLS*2);
    ushort_t* owlo  = (ushort_t*)alloc((size_t)IN_DIM*GCOLS*2);
    ushort_t* o2hi  = (ushort_t*)alloc((size_t)OUT_DIM*GCOLS*2);
    ushort_t* o2lo  = (ushort_t*)alloc((size_t)OUT_DIM*GCOLS*2);
    unsigned* maskJ = (unsigned*)alloc((size_t)N_NODES*NWORDS*4);     // 2 MB
    float*    ssrc  = (float*)   alloc((size_t)HEADS*N_NODES*4);
    float*    sdst  = (float*)   alloc((size_t)HEADS*N_NODES*4);
    float*    zbuf  = (float*)   alloc((size_t)HEADS*2*N_NODES*4);
    float*    msd   = (float*)   alloc(256);

    pack_kernel<<<N_NODES/4, 256, 0, stream>>>(adj, maskJ);
    cvt_hilo<<<(N_NODES*IN_DIM)/1024, 256, 0, stream>>>(label, xlhi, xllo, N_NODES*IN_DIM);
    cvt_hilo<<<(GCOLS*IN_DIM)/1024, 256, 0, stream>>>(W1, w1hi, w1lo, GCOLS*IN_DIM);
    cvt_hilo<<<(GCOLS*IN_DIM)/1024, 256, 0, stream>>>(W2, w2hi, w2lo, GCOLS*IN_DIM);
    cvt_hilo<<<(IN_DIM*GCOLS)/1024, 256, 0, stream>>>(out_w, owhi, owlo, IN_DIM*GCOLS);
    cvt_hilo<<<(OUT_DIM*GCOLS)/1024, 256, 0, stream>>>(out2_w, o2hi, o2lo, OUT_DIM*GCOLS);

    auto layer = [&](const ushort_t* Whi, const ushort_t* Wlo, const float* avec,
                     const ushort_t* hhi, const ushort_t* hlo, int K) {
        zero_kernel<<<(2*HEADS*N_NODES)/256, 256, 0, stream>>>(ssrc, 2*HEADS*N_NODES);
        // gT[c][j] (+ scaled s_src/s_dst atomics):  gT = W @ h^T
        gemm_hilo<<<dim3(N_NODES/128, GCOLS/128), 256, 0, stream>>>(
            Whi, Wlo, hhi, hlo, nullptr, nullptr, gThi, nullptr,
            avec, ssrc, sdst, GCOLS, N_NODES, K);
        maxsd_kernel<<<HEADS, 256, 0, stream>>>(sdst, msd);
        attg_kernel<<<dim3(N_NODES/128, HEADS*2, 2), 256, 0, stream>>>(
            gThi, maskJ, ssrc, msd, sdst, part0, part1, zbuf);
        reduce_elu2<<<(N_NODES*GCOLS)/1024, 256, 0, stream>>>(part0, part1, zbuf, hchi, hclo);
    };

    layer(w1hi, w1lo, a1, xlhi, xllo, IN_DIM);
    // x1 = hcat @ out_w^T + out_b  -> split bf16 (overwrites label slot)
    gemm_hilo<<<dim3(IN_DIM/128, N_NODES/128), 256, 0, stream>>>(
        hchi, hclo, owhi, owlo, out_b, nullptr, xlhi, xllo,
        nullptr, nullptr, nullptr, N_NODES, IN_DIM, GCOLS);
    layer(w2hi, w2lo, a2, xlhi, xllo, IN_DIM);
    // out = hcat @ out2_w^T + out2_b  (fp32, N=32 guarded)
    gemm_hilo<<<dim3(1, N_NODES/128), 256, 0, stream>>>(
        hchi, hclo, o2hi, o2lo, out2_b, out, nullptr, nullptr,
        nullptr, nullptr, nullptr, N_NODES, OUT_DIM, GCOLS);
}